// Round 8
// baseline (707.616 us; speedup 1.0000x reference)
//
#include <hip/hip_runtime.h>
#include <stdint.h>
#include <stddef.h>

// ---------------------------------------------------------------------------
// Fused GQA attention block: QKV proj + half-split RoPE + flash attention +
// output proj. fp16 MFMA (16x16x32) everywhere, fp32 accumulate/softmax.
// R8: GEMM K-loop register-pipelined: fragments for phase p+1 are ds_read
// during phase p's MFMA (compiler inserts counted lgkm waits); only TWO
// barriers per K-tile (P2 / P4) with counted vmcnt(8)/(4); stages split
// pre-barrier (S1,S2 -> kc1 of next tile) and post-barrier (S3,S4 -> kc0 of
// tile t+2). DS traffic now overlaps the MFMA pipe instead of serializing.
// ---------------------------------------------------------------------------

typedef _Float16 half_t;
typedef __attribute__((ext_vector_type(4))) _Float16 f16x4;
typedef __attribute__((ext_vector_type(8))) _Float16 f16x8;
typedef __attribute__((ext_vector_type(4))) float f32x4;

#define NB 2
#define NL 2048
#define ND 4096
#define NH 32
#define NKV 8
#define NHD 128
#define NG 4               // H / KV
#define NQKV 6144          // H*HD + 2*KV*HD
#define QK_SCALE 0.08838834764831845f   // HD^-0.5
#define RLOG2E 1.4426950408889634f
#define M0 6.0f            // fixed softmax reference (scores ~N(0,1.64^2))
#define THR 8.0f           // defer-max threshold (fallback if mx > M0+THR)

// async global->LDS, 16B per lane. LDS dest must be wave-uniform base;
// lane i lands at base + i*16 (HW-defined linear scatter).
static __device__ __forceinline__ void gll16(const void* g, void* l) {
  __builtin_amdgcn_global_load_lds(
      (__attribute__((address_space(1))) void*)(void*)(g),
      (__attribute__((address_space(3))) void*)(l),
      16, 0, 0);
}

// ---------------------------------------------------------------------------
// elementwise fp32 -> fp16 (vectorized: float4 in, 4xfp16 out)
// ---------------------------------------------------------------------------
__global__ void convert_f32_f16_kernel(const float* __restrict__ in,
                                       half_t* __restrict__ out, int n4) {
  int i = blockIdx.x * 256 + threadIdx.x;
  if (i >= n4) return;
  const float4 v = reinterpret_cast<const float4*>(in)[i];
  f16x4 o;
  o[0] = (half_t)v.x; o[1] = (half_t)v.y; o[2] = (half_t)v.z; o[3] = (half_t)v.w;
  reinterpret_cast<f16x4*>(out)[i] = o;
}

// ---------------------------------------------------------------------------
// W [K,N] fp32 row-major  ->  Wt [N,K] fp16 row-major (LDS 32x32 tile transpose)
// ---------------------------------------------------------------------------
__global__ void wtrans_kernel(const float* __restrict__ W,
                              half_t* __restrict__ Wt, int K, int N) {
  __shared__ float tile[32][33];
  const int n0 = blockIdx.x * 32;
  const int k0 = blockIdx.y * 32;
  const int tx = threadIdx.x, ty = threadIdx.y;   // block (32,8)
#pragma unroll
  for (int r = 0; r < 32; r += 8)
    tile[ty + r][tx] = W[(size_t)(k0 + ty + r) * N + n0 + tx];
  __syncthreads();
#pragma unroll
  for (int r = 0; r < 32; r += 8)
    Wt[(size_t)(n0 + ty + r) * K + k0 + tx] = (half_t)tile[tx][ty + r];
}

// ---------------------------------------------------------------------------
// GEMM: C[M,N] = A[M,K] * Bt[N,K]^T (+ 3-way bias), A/Bt fp16, C fp32/fp16.
// 256x256 tile, 8 waves (2M x 4N, each 128x64 out), BK=64 as 2 K-halves.
// LDS [2buf][2kh][256 rows][32 halfs] per array (128 KB total).
//
// Register-pipelined 4-phase schedule per K-tile t (buf = t&1):
//  P1: ds_read ah0 (kc0 rows 64..127)         ; MFMA af0 x bf0 -> acc[0..3]
//  P2: stage S1=A(t+1)kc1, S2=B(t+1)kc1; vmcnt(8); BARRIER;
//      ds_read af1 (kc1 rows 0..63)           ; MFMA ah0 x bf0 -> acc[4..7]
//  P3: ds_read bf1, ah1 (kc1)                 ; MFMA af1 x bf1 -> acc[0..3]
//  P4: lgkm0+vmcnt(4); BARRIER; stage S3=A(t+2)kc0, S4=B(t+2)kc0;
//      ds_read af0',bf0' (tile t+1 kc0, buf^1); MFMA ah1 x bf1 -> acc[4..7]
//
// RAW: F3/F4 (kc1 of t, staged S1/S2(t-1)) retired by P2's vmcnt(8) [after
//   S1,S2(t) issue, outstanding = S3,S4(t-1)+S1,S2(t) = 8] + barrier.
//   F1'/F2' (kc0 of t+1, staged S3/S4(t-1)) retired by P4's vmcnt(4)
//   [outstanding after = S1,S2(t)] + barrier.
// WAR: S1/S2(t) overwrite [buf^1][1], whose readers (af1/bf1/ah1 of t-1)
//   retired before their consuming MFMAs, all before t-1 P4's lgkm0+barrier.
//   S3/S4(t) are POST-barrier: [buf][0] readers (af0/bf0 consumed P1, ah0
//   consumed P2) retired before each wave's P2/P3 bodies, hence before all
//   waves reach the P4 barrier. lgkm0 at P4 pins each wave's own in-flight
//   ds_reads (ah1/bf1) before the barrier so S1(t+1) cannot race them.
// Tail: stages guarded (S1,S2: t+1<NT; S3,S4: t+2<NT); P2 vmcnt = 8 if
//   t+1<NT else 0 (then outstanding = S1,S2(t-1) only); P4 sync skipped at
//   t = NT-1 (no next tile, no further LDS writes).
// ---------------------------------------------------------------------------
template <typename OutT>
__global__ __launch_bounds__(512, 2) void gemm256_kernel(
    const half_t* __restrict__ A, const half_t* __restrict__ Bt,
    const float* __restrict__ B0, const float* __restrict__ B1,
    const float* __restrict__ B2, OutT* __restrict__ C,
    int M, int N, int K) {
  __shared__ __align__(16) half_t As[2][2][256 * 32];   // [buf][kh] 16KB each
  __shared__ __align__(16) half_t Bs[2][2][256 * 32];

  const int tid = threadIdx.x;
  const int wave = tid >> 6, lane = tid & 63;
  const int r16 = lane & 15, quad = lane >> 4;
  const int wm = wave >> 2, wn = wave & 3;   // 2M x 4N wave grid

  // T1: XCD-chunked swizzle of linear block id (nwg % 8 == 0 for our grids)
  const int nbx = N >> 8;
  const int lid = (int)(blockIdx.y * gridDim.x + blockIdx.x);
  const int nwg = (int)(gridDim.x * gridDim.y);
  const int cpx = nwg >> 3;
  const int swz = (lid & 7) * cpx + (lid >> 3);
  const int brow = (swz / nbx) * 256;
  const int bcol = (swz % nbx) * 256;

  const int NT = K >> 6;   // K/64 tiles

  // half-tile stage: 256 rows x 32 halfs (64B/row), 1024 slots, 2/thread.
  // slot s: row=s>>2, LDS chunk s&3 holds global chunk (s&3)^((row>>1)&3).
  auto stA = [&](int t, int kh) {
    const int buf = t & 1;
    const int k0 = (t << 6) + (kh << 5);
#pragma unroll
    for (int j = 0; j < 2; ++j) {
      const int s = j * 512 + wave * 64 + lane;
      const int row = s >> 2;
      const int cg = (s & 3) ^ ((row >> 1) & 3);
      gll16(A + (size_t)(brow + row) * K + k0 + cg * 8,
            &As[buf][kh][(j * 512 + wave * 64) * 8]);
    }
  };
  auto stB = [&](int t, int kh) {
    const int buf = t & 1;
    const int k0 = (t << 6) + (kh << 5);
#pragma unroll
    for (int j = 0; j < 2; ++j) {
      const int s = j * 512 + wave * 64 + lane;
      const int row = s >> 2;
      const int cg = (s & 3) ^ ((row >> 1) & 3);
      gll16(Bt + (size_t)(bcol + row) * K + k0 + cg * 8,
            &Bs[buf][kh][(j * 512 + wave * 64) * 8]);
    }
  };

  f32x4 acc[8][4] = {};
  const int csw = (quad ^ ((r16 >> 1) & 3)) << 3;   // swizzled chunk (halfs)

  // prologue: kc0(0), kc1(0), kc0(1) = 12 loads; retire tile0 kc0 (vmcnt(8))
  stA(0, 0); stB(0, 0); stA(0, 1); stB(0, 1); stA(1, 0); stB(1, 0);
  asm volatile("s_waitcnt vmcnt(8)" ::: "memory");
  __builtin_amdgcn_s_barrier();
  __builtin_amdgcn_sched_barrier(0);

  f16x8 af0[4], bf0[4], ah0[4], af1[4], bf1[4], ah1[4];
  {
    const half_t* Ak0 = &As[0][0][0];
    const half_t* Bk0 = &Bs[0][0][0];
#pragma unroll
    for (int mi = 0; mi < 4; ++mi)
      af0[mi] = *reinterpret_cast<const f16x8*>(
          &Ak0[(wm * 128 + mi * 16 + r16) * 32 + csw]);
#pragma unroll
    for (int ni = 0; ni < 4; ++ni)
      bf0[ni] = *reinterpret_cast<const f16x8*>(
          &Bk0[(wn * 64 + ni * 16 + r16) * 32 + csw]);
  }

  for (int t = 0; t < NT; ++t) {
    const int buf = t & 1;
    const half_t* Ak0 = &As[buf][0][0];
    const half_t* Ak1 = &As[buf][1][0];
    const half_t* Bk1 = &Bs[buf][1][0];
    const half_t* An0 = &As[buf ^ 1][0][0];
    const half_t* Bn0 = &Bs[buf ^ 1][0][0];

    // ---- P1: read ah0 (next phase) || MFMA af0 x bf0 ----
#pragma unroll
    for (int mi = 0; mi < 4; ++mi)
      ah0[mi] = *reinterpret_cast<const f16x8*>(
          &Ak0[(wm * 128 + 64 + mi * 16 + r16) * 32 + csw]);
#pragma unroll
    for (int mi = 0; mi < 4; ++mi)
#pragma unroll
      for (int ni = 0; ni < 4; ++ni)
        acc[mi][ni] = __builtin_amdgcn_mfma_f32_16x16x32_f16(
            af0[mi], bf0[ni], acc[mi][ni], 0, 0, 0);

    // ---- P2: stage S1,S2 ; vmcnt ; barrier ; read af1 || MFMA ah0 x bf0 ----
    if (t + 1 < NT) {
      stA(t + 1, 1); stB(t + 1, 1);
      asm volatile("s_waitcnt vmcnt(8)" ::: "memory");
    } else {
      asm volatile("s_waitcnt vmcnt(0)" ::: "memory");
    }
    __builtin_amdgcn_s_barrier();
    __builtin_amdgcn_sched_barrier(0);
#pragma unroll
    for (int mi = 0; mi < 4; ++mi)
      af1[mi] = *reinterpret_cast<const f16x8*>(
          &Ak1[(wm * 128 + mi * 16 + r16) * 32 + csw]);
#pragma unroll
    for (int mi = 0; mi < 4; ++mi)
#pragma unroll
      for (int ni = 0; ni < 4; ++ni)
        acc[mi + 4][ni] = __builtin_amdgcn_mfma_f32_16x16x32_f16(
            ah0[mi], bf0[ni], acc[mi + 4][ni], 0, 0, 0);

    // ---- P3: read bf1, ah1 || MFMA af1 x bf1 ----
#pragma unroll
    for (int ni = 0; ni < 4; ++ni)
      bf1[ni] = *reinterpret_cast<const f16x8*>(
          &Bk1[(wn * 64 + ni * 16 + r16) * 32 + csw]);
#pragma unroll
    for (int mi = 0; mi < 4; ++mi)
      ah1[mi] = *reinterpret_cast<const f16x8*>(
          &Ak1[(wm * 128 + 64 + mi * 16 + r16) * 32 + csw]);
#pragma unroll
    for (int mi = 0; mi < 4; ++mi)
#pragma unroll
      for (int ni = 0; ni < 4; ++ni)
        acc[mi][ni] = __builtin_amdgcn_mfma_f32_16x16x32_f16(
            af1[mi], bf1[ni], acc[mi][ni], 0, 0, 0);

    // ---- P4: lgkm0+vmcnt(4) ; barrier ; stage S3,S4 ; read next-tile kc0
    //          || MFMA ah1 x bf1 ----
    if (t + 1 < NT) {
      asm volatile("s_waitcnt vmcnt(4) lgkmcnt(0)" ::: "memory");
      __builtin_amdgcn_s_barrier();
      __builtin_amdgcn_sched_barrier(0);
      if (t + 2 < NT) { stA(t + 2, 0); stB(t + 2, 0); }
#pragma unroll
      for (int mi = 0; mi < 4; ++mi)
        af0[mi] = *reinterpret_cast<const f16x8*>(
            &An0[(wm * 128 + mi * 16 + r16) * 32 + csw]);
#pragma unroll
      for (int ni = 0; ni < 4; ++ni)
        bf0[ni] = *reinterpret_cast<const f16x8*>(
            &Bn0[(wn * 64 + ni * 16 + r16) * 32 + csw]);
    }
#pragma unroll
    for (int mi = 0; mi < 4; ++mi)
#pragma unroll
      for (int ni = 0; ni < 4; ++ni)
        acc[mi + 4][ni] = __builtin_amdgcn_mfma_f32_16x16x32_f16(
            ah1[mi], bf1[ni], acc[mi + 4][ni], 0, 0, 0);
  }

  // epilogue: D row = (lane>>4)*4 + reg, col = lane&15 (verified C/D layout)
#pragma unroll
  for (int ni = 0; ni < 4; ++ni) {
    const int col = bcol + wn * 64 + ni * 16 + r16;
    float bv = 0.0f;
    if (B0) bv = (col < ND) ? B0[col]
                            : (col < ND + NKV * NHD ? B1[col - ND]
                                                    : B2[col - ND - NKV * NHD]);
#pragma unroll
    for (int mi = 0; mi < 8; ++mi) {
      const int row0 = brow + wm * 128 + mi * 16 + quad * 4;
#pragma unroll
      for (int i = 0; i < 4; ++i)
        C[(size_t)(row0 + i) * N + col] = (OutT)(acc[mi][ni][i] + bv);
    }
  }
}

// ---------------------------------------------------------------------------
// RoPE (half-split) + reshape for Q and K from merged raw fp16 [B*L, 6144].
// hp<32: Q head hp (QK_SCALE folded); else K head hp-32.
// ---------------------------------------------------------------------------
__global__ void ropepack_kernel(const half_t* __restrict__ rawh,
                                half_t* __restrict__ qb,
                                half_t* __restrict__ kb) {
  const size_t idx = (size_t)blockIdx.x * 256 + threadIdx.x;
  const int d = (int)(idx & 63);
  size_t t = idx >> 6;
  const int hp = (int)(t % (NH + NKV)); t /= (NH + NKV);
  const int l = (int)(t % NL);
  const int b = (int)(t / NL);
  const bool isQ = hp < NH;
  const int col0 = isQ ? hp * NHD : ND + (hp - NH) * NHD;
  const half_t* src = rawh + ((size_t)b * NL + l) * NQKV + col0;
  const float x1 = (float)src[d];
  const float x2 = (float)src[d + 64];
  const float inv_freq = exp2f(-(float)d * 0.20762050593045935f);
  const float ang = (float)l * inv_freq;
  float sn, cs;
  __sincosf(ang, &sn, &cs);
  const float scale = isQ ? QK_SCALE : 1.0f;
  half_t* dst = isQ ? qb + ((size_t)(b * NH + hp) * NL + l) * NHD
                    : kb + ((size_t)(b * NKV + (hp - NH)) * NL + l) * NHD;
  dst[d]      = (half_t)((x1 * cs - x2 * sn) * scale);
  dst[d + 64] = (half_t)((x2 * cs + x1 * sn) * scale);
}

// ---------------------------------------------------------------------------
// V: merged raw fp16 cols [5120,6144) -> Vt [B, KV, HD, L] fp16 (transpose)
// ---------------------------------------------------------------------------
__global__ void vtrans16_kernel(const half_t* __restrict__ rawh,
                                half_t* __restrict__ Vt) {
  __shared__ half_t tile[32][34];
  const int bkv = blockIdx.z;
  const int l0 = blockIdx.x * 32;
  const int d0 = blockIdx.y * 32;
  const int b = bkv / NKV, kvh = bkv % NKV;
  const int tx = threadIdx.x, ty = threadIdx.y;   // block (32,8)
#pragma unroll
  for (int r = 0; r < 32; r += 8)
    tile[ty + r][tx] = rawh[(size_t)(b * NL + l0 + ty + r) * NQKV
                            + ND + NKV * NHD + kvh * NHD + d0 + tx];
  __syncthreads();
  half_t* dst = Vt + (size_t)bkv * NHD * NL;
#pragma unroll
  for (int r = 0; r < 32; r += 8)
    dst[(size_t)(d0 + ty + r) * NL + l0 + tx] = tile[tx][ty + r];
}

// ---------------------------------------------------------------------------
// Flash attention (non-causal, GQA). 8 waves x 32 Q-rows = 256 rows/block.
// K/V tiles (64 keys) LDS-staged via global_load_lds, double-buffered,
// XOR chunk-swizzled. Softmax: fixed reference M0 (no per-tile max reduce),
// per-lane deferred row-sum (one reduce in epilogue), rare wave-uniform
// fallback rescale keeps arbitrary-data correctness.
// ---------------------------------------------------------------------------
#define KVB 64

__global__ __launch_bounds__(512, 2) void attn_kernel(
    const half_t* __restrict__ Q,   // [B,H,L,HD] scaled
    const half_t* __restrict__ Kh,  // [B,KV,L,HD]
    const half_t* __restrict__ Vt,  // [B,KV,HD,L]
    half_t* __restrict__ O) {
  __shared__ half_t Ks[2][KVB * NHD];   // 2 x 16KB
  __shared__ half_t Vs[2][NHD * KVB];   // 2 x 16KB
  __shared__ half_t Ps[8][16 * 64];     // 16KB, per-wave P tile

  const int tid = threadIdx.x;
  const int wave = tid >> 6, lane = tid & 63;
  const int r16 = lane & 15, quad = lane >> 4;
  const int r7 = r16 & 7;

  // XCD-chunked swizzle: 64 consecutive work-items per XCD (512 = 8*64)
  const int bid = (int)blockIdx.x;
  const int swz = (bid & 7) * 64 + (bid >> 3);
  const int nqt = NL / 256;                    // 8
  const int bh = swz / nqt, qt = swz % nqt;
  const int b = bh / NH, h = bh % NH;
  const int kvh = h / NG;

  const int qrow0 = qt * 256 + wave * 32;
  const half_t* Qb = Q  + ((size_t)(b * NH + h) * NL + qrow0) * NHD;
  const half_t* Kb = Kh + ((size_t)(b * NKV + kvh) * NL) * NHD;
  const half_t* Vb = Vt + ((size_t)(b * NKV + kvh) * NHD) * NL;
  half_t* Pw = &Ps[wave][0];

  // ---- stage(buf, n0): K tile 1024 slots, V tile 1024 slots (16B each) ----
  auto stage = [&](int buf, int n0) {
#pragma unroll
    for (int j = 0; j < 2; ++j) {
      const int slot = j * 512 + wave * 64 + lane;
      {
        const int row = slot >> 4;                    // key row 0..63
        const int c = (slot & 15) ^ (row & 7);        // global chunk
        gll16(Kb + (size_t)(n0 + row) * NHD + c * 8,
              &Ks[buf][(j * 512 + wave * 64) * 8]);
      }
      {
        const int row = slot >> 3;                    // d row 0..127
        const int c = (slot & 7) ^ (row & 7);
        gll16(Vb + (size_t)row * NL + n0 + c * 8,
              &Vs[buf][(j * 512 + wave * 64) * 8]);
      }
    }
  };

  stage(0, 0);

  // Q fragments: 2 row-tiles x 4 k-chunks
  f16x8 qf[2][4];
#pragma unroll
  for (int rt = 0; rt < 2; ++rt)
#pragma unroll
    for (int c = 0; c < 4; ++c)
      qf[rt][c] = *reinterpret_cast<const f16x8*>(
          &Qb[(size_t)(rt * 16 + r16) * NHD + c * 32 + quad * 8]);

  f32x4 oacc[2][8];
  float m_run[2][4], lsum[2][4];
#pragma unroll
  for (int rt = 0; rt < 2; ++rt) {
#pragma unroll
    for (int i = 0; i < 4; ++i) { m_run[rt][i] = M0; lsum[rt][i] = 0.0f; }
#pragma unroll
    for (int dt = 0; dt < 8; ++dt) oacc[rt][dt] = (f32x4){0.f, 0.f, 0.f, 0.f};
  }

  // P read swizzle (row = r16): mask = (r16&7) ^ ((r16>>3)*5)
  const int swzread = r7 ^ ((r16 >> 3) * 5);

  asm volatile("s_waitcnt vmcnt(0)" ::: "memory");
  __syncthreads();

  int cur = 0;
  for (int t = 0; t < NL / KVB; ++t, cur ^= 1) {
    if (t + 1 < NL / KVB) stage(cur ^ 1, (t + 1) * KVB);

    const half_t* Kc = &Ks[cur][0];
    const half_t* Vc = &Vs[cur][0];

    // ---- S = Q K^T (swizzled K reads) ----
    f32x4 s[2][4] = {};
#pragma unroll
    for (int c = 0; c < 4; ++c) {
      const int ch = ((c * 4 + quad) ^ r7) * 8;
#pragma unroll
      for (int nt = 0; nt < 4; ++nt) {
        f16x8 kf = *reinterpret_cast<const f16x8*>(&Kc[(nt * 16 + r16) * NHD + ch]);
        s[0][nt] = __builtin_amdgcn_mfma_f32_16x16x32_f16(qf[0][c], kf, s[0][nt], 0, 0, 0);
        s[1][nt] = __builtin_amdgcn_mfma_f32_16x16x32_f16(qf[1][c], kf, s[1][nt], 0, 0, 0);
      }
    }

    // ---- fallback check: any lane-local score above M0+THR? (no reduce) ----
    float mx[2][4];
    bool need = false;
#pragma unroll
    for (int rt = 0; rt < 2; ++rt)
#pragma unroll
      for (int i = 0; i < 4; ++i) {
        mx[rt][i] = fmaxf(fmaxf(s[rt][0][i], s[rt][1][i]),
                          fmaxf(s[rt][2][i], s[rt][3][i]));
        need = need || (mx[rt][i] > m_run[rt][i] + THR);
      }
    if (__any(need ? 1 : 0)) {   // rare: full reduce + rescale (correctness)
#pragma unroll
      for (int rt = 0; rt < 2; ++rt)
#pragma unroll
        for (int i = 0; i < 4; ++i) {
          float m = mx[rt][i];
#pragma unroll
          for (int off = 1; off < 16; off <<= 1)
            m = fmaxf(m, __shfl_xor(m, off));
          const float mn = fmaxf(m_run[rt][i], m);
          const float corr = exp2f((m_run[rt][i] - mn) * RLOG2E);
          m_run[rt][i] = mn;
          lsum[rt][i] *= corr;
#pragma unroll
          for (int dt = 0; dt < 8; ++dt) oacc[rt][dt][i] *= corr;
        }
    }

    // ---- P = exp(S - m), per-lane partial sums, swizzled LDS writes ----
    f16x8 pa[2][2];
#pragma unroll
    for (int rt = 0; rt < 2; ++rt) {
#pragma unroll
      for (int i = 0; i < 4; ++i) {
        const float mrl = m_run[rt][i] * RLOG2E;
        float p[4];
#pragma unroll
        for (int nt = 0; nt < 4; ++nt)
          p[nt] = exp2f(s[rt][nt][i] * RLOG2E - mrl);
        lsum[rt][i] += (p[0] + p[1]) + (p[2] + p[3]);
        const int row = quad * 4 + i;
        const int swzr = (row & 7) ^ ((row >> 3) * 5);
#pragma unroll
        for (int nt = 0; nt < 4; ++nt)
          Pw[row * 64 + (((nt * 2 + (r16 >> 3)) ^ swzr) * 8) + r7] = (half_t)p[nt];
      }
      // A-fragments (wave-private LDS; in-order DS pipe, no barrier)
      pa[rt][0] = *reinterpret_cast<const f16x8*>(&Pw[r16 * 64 + ((quad ^ swzread) * 8)]);
      pa[rt][1] = *reinterpret_cast<const f16x8*>(&Pw[r16 * 64 + (((4 + quad) ^ swzread) * 8)]);
    }

    // ---- O += P V (swizzled V reads, shared across both row-tiles) ----
    const int ch0 = (quad ^ r7) * 8;
    const int ch1 = ((4 + quad) ^ r7) * 8;
#pragma unroll
    for (int dt = 0; dt < 8; ++dt) {
      const int row = dt * 16 + r16;
      f16x8 v0 = *reinterpret_cast<const f16x8*>(&Vc[row * 64 + ch0]);
      f16x8 v1 = *reinterpret_cast<const f16x8*>(&Vc[row * 64 + ch1]);
      oacc[0][dt] = __builtin_amdgcn_mfma_f32_16x16x32_f16(pa[0][0], v0, oacc[0][dt], 0, 0, 0);
      oacc[0][dt] = __builtin_amdgcn_mfma_f32_16x16x32_f16(pa[0][1], v1, oacc[0][dt], 0, 0, 0);
      oacc[1][dt] = __builtin_amdgcn_mfma_f32_16x16x32_f16(pa[1][0], v0, oacc[1][dt], 0, 0, 0);
      oacc[1][dt] = __builtin_amdgcn_mfma_f32_16x16x32_f16(pa[1][1], v1, oacc[1][dt], 0, 0, 0);
    }

    asm volatile("s_waitcnt vmcnt(0)" ::: "memory");
    __syncthreads();
  }

  // ---- epilogue: one deferred row-sum reduce, normalize, write fp16 ----
  half_t* Ob = O + ((size_t)(b * NL) + qrow0) * (NH * NHD) + (size_t)h * NHD;
#pragma unroll
  for (int rt = 0; rt < 2; ++rt)
#pragma unroll
    for (int i = 0; i < 4; ++i) {
      float l = lsum[rt][i];
#pragma unroll
      for (int off = 1; off < 16; off <<= 1)
        l += __shfl_xor(l, off);
      const float inv = 1.0f / l;
      const int rl = rt * 16 + quad * 4 + i;
#pragma unroll
      for (int dt = 0; dt < 8; ++dt)
        Ob[(size_t)rl * (NH * NHD) + dt * 16 + r16] =
            (half_t)(oacc[rt][dt][i] * inv);
    }
}

// ---------------------------------------------------------------------------
extern "C" void kernel_launch(void* const* d_in, const int* in_sizes, int n_in,
                              void* d_out, int out_size, void* d_ws, size_t ws_size,
                              hipStream_t stream) {
  const float* x  = (const float*)d_in[0];
  const float* Wq = (const float*)d_in[1];
  const float* bq = (const float*)d_in[2];
  const float* Wk = (const float*)d_in[3];
  const float* bk = (const float*)d_in[4];
  const float* Wv = (const float*)d_in[5];
  const float* bv = (const float*)d_in[6];
  const float* Wo = (const float*)d_in[7];
  float* out = (float*)d_out;

  char* ws = (char*)d_ws;
  size_t off = 0;
  auto alloc = [&](size_t bytes) {
    size_t cur = off;
    off += (bytes + 255) & ~(size_t)255;
    return cur;
  };
  const size_t M = (size_t)NB * NL;  // 4096 token rows
  // buffer plan (~185 MB):
  half_t* xb   = (half_t*)(ws + alloc(M * ND * 2));            // x fp16; reused as AttnOut
  half_t* wqkv = (half_t*)(ws + alloc((size_t)NQKV * ND * 2)); // [Wq;Wk;Wv]^T; reused for Wo^T
  half_t* rawh = (half_t*)(ws + alloc(M * NQKV * 2));          // merged QKV raw fp16
  half_t* qb   = (half_t*)(ws + alloc(M * (size_t)(NH * NHD) * 2));
  half_t* kb   = (half_t*)(ws + alloc(M * (size_t)(NKV * NHD) * 2));
  half_t* vt   = (half_t*)(ws + alloc(M * (size_t)(NKV * NHD) * 2));

  // 1) x -> fp16
  {
    int n4 = (int)(M * ND / 4);
    convert_f32_f16_kernel<<<dim3((n4 + 255) / 256), dim3(256), 0, stream>>>(x, xb, n4);
  }
  // 2) weight transposes into merged [6144][4096] fp16
  wtrans_kernel<<<dim3(ND / 32, ND / 32), dim3(32, 8), 0, stream>>>(
      Wq, wqkv, ND, ND);
  wtrans_kernel<<<dim3((NKV * NHD) / 32, ND / 32), dim3(32, 8), 0, stream>>>(
      Wk, wqkv + (size_t)ND * ND, ND, NKV * NHD);
  wtrans_kernel<<<dim3((NKV * NHD) / 32, ND / 32), dim3(32, 8), 0, stream>>>(
      Wv, wqkv + (size_t)(ND + NKV * NHD) * ND, ND, NKV * NHD);

  // 3) merged QKV GEMM -> rawh fp16 (bias fused, 3-way select)
  gemm256_kernel<half_t><<<dim3(NQKV / 256, M / 256), dim3(512), 0, stream>>>(
      xb, wqkv, bq, bk, bv, rawh, (int)M, NQKV, ND);

  // 4) RoPE+pack Q,K; transpose V
  ropepack_kernel<<<dim3((unsigned)(M * (NH + NKV) * 64 / 256)), dim3(256), 0, stream>>>(
      rawh, qb, kb);
  vtrans16_kernel<<<dim3(NL / 32, NHD / 32, NB * NKV), dim3(32, 8), 0, stream>>>(rawh, vt);

  // 5) Wo^T into wqkv (dead after step 3; stream order guarantees safety)
  wtrans_kernel<<<dim3(ND / 32, ND / 32), dim3(32, 8), 0, stream>>>(Wo, wqkv, NH * NHD, ND);

  // 6) attention -> xb (reused as AttnOut, [B*L, H*HD] fp16)
  attn_kernel<<<dim3(NB * NH * (NL / 256)), dim3(512), 0, stream>>>(qb, kb, vt, xb);

  // 7) output projection -> d_out (fp32)
  gemm256_kernel<float><<<dim3(ND / 256, M / 256), dim3(512), 0, stream>>>(
      xb, wqkv, nullptr, nullptr, nullptr, out, (int)M, ND, ND);
}

// Round 9
// 706.953 us; speedup vs baseline: 1.0009x; 1.0009x over previous
//
#include <hip/hip_runtime.h>
#include <stdint.h>
#include <stddef.h>

// ---------------------------------------------------------------------------
// Fused GQA attention block: QKV proj + half-split RoPE + flash attention +
// output proj. fp16 MFMA (16x16x32) everywhere, fp32 accumulate/softmax.
// R8: GEMM K-loop register-pipelined: fragments for phase p+1 are ds_read
// during phase p's MFMA (compiler inserts counted lgkm waits); only TWO
// barriers per K-tile (P2 / P4) with counted vmcnt(8)/(4); stages split
// pre-barrier (S1,S2 -> kc1 of next tile) and post-barrier (S3,S4 -> kc0 of
// tile t+2). DS traffic now overlaps the MFMA pipe instead of serializing.
// ---------------------------------------------------------------------------

typedef _Float16 half_t;
typedef __attribute__((ext_vector_type(4))) _Float16 f16x4;
typedef __attribute__((ext_vector_type(8))) _Float16 f16x8;
typedef __attribute__((ext_vector_type(4))) float f32x4;

#define NB 2
#define NL 2048
#define ND 4096
#define NH 32
#define NKV 8
#define NHD 128
#define NG 4               // H / KV
#define NQKV 6144          // H*HD + 2*KV*HD
#define QK_SCALE 0.08838834764831845f   // HD^-0.5
#define RLOG2E 1.4426950408889634f
#define M0 6.0f            // fixed softmax reference (scores ~N(0,1.64^2))
#define THR 8.0f           // defer-max threshold (fallback if mx > M0+THR)

// async global->LDS, 16B per lane. LDS dest must be wave-uniform base;
// lane i lands at base + i*16 (HW-defined linear scatter).
static __device__ __forceinline__ void gll16(const void* g, void* l) {
  __builtin_amdgcn_global_load_lds(
      (__attribute__((address_space(1))) void*)(void*)(g),
      (__attribute__((address_space(3))) void*)(l),
      16, 0, 0);
}

// ---------------------------------------------------------------------------
// elementwise fp32 -> fp16 (vectorized: float4 in, 4xfp16 out)
// ---------------------------------------------------------------------------
__global__ void convert_f32_f16_kernel(const float* __restrict__ in,
                                       half_t* __restrict__ out, int n4) {
  int i = blockIdx.x * 256 + threadIdx.x;
  if (i >= n4) return;
  const float4 v = reinterpret_cast<const float4*>(in)[i];
  f16x4 o;
  o[0] = (half_t)v.x; o[1] = (half_t)v.y; o[2] = (half_t)v.z; o[3] = (half_t)v.w;
  reinterpret_cast<f16x4*>(out)[i] = o;
}

// ---------------------------------------------------------------------------
// W [K,N] fp32 row-major  ->  Wt [N,K] fp16 row-major (LDS 32x32 tile transpose)
// ---------------------------------------------------------------------------
__global__ void wtrans_kernel(const float* __restrict__ W,
                              half_t* __restrict__ Wt, int K, int N) {
  __shared__ float tile[32][33];
  const int n0 = blockIdx.x * 32;
  const int k0 = blockIdx.y * 32;
  const int tx = threadIdx.x, ty = threadIdx.y;   // block (32,8)
#pragma unroll
  for (int r = 0; r < 32; r += 8)
    tile[ty + r][tx] = W[(size_t)(k0 + ty + r) * N + n0 + tx];
  __syncthreads();
#pragma unroll
  for (int r = 0; r < 32; r += 8)
    Wt[(size_t)(n0 + ty + r) * K + k0 + tx] = (half_t)tile[tx][ty + r];
}

// ---------------------------------------------------------------------------
// GEMM: C[M,N] = A[M,K] * Bt[N,K]^T (+ 3-way bias), A/Bt fp16, C fp32/fp16.
// 256x256 tile, 8 waves (2M x 4N, each 128x64 out), BK=64 as 2 K-halves.
// LDS [2buf][2kh][256 rows][32 halfs] per array (128 KB total).
//
// Register-pipelined 4-phase schedule per K-tile t (buf = t&1):
//  P1: ds_read ah0 (kc0 rows 64..127)         ; MFMA af0 x bf0 -> acc[0..3]
//  P2: stage S1=A(t+1)kc1, S2=B(t+1)kc1; vmcnt(8); BARRIER;
//      ds_read af1 (kc1 rows 0..63)           ; MFMA ah0 x bf0 -> acc[4..7]
//  P3: ds_read bf1, ah1 (kc1)                 ; MFMA af1 x bf1 -> acc[0..3]
//  P4: lgkm0+vmcnt(4); BARRIER; stage S3=A(t+2)kc0, S4=B(t+2)kc0;
//      ds_read af0',bf0' (tile t+1 kc0, buf^1); MFMA ah1 x bf1 -> acc[4..7]
//
// RAW: F3/F4 (kc1 of t, staged S1/S2(t-1)) retired by P2's vmcnt(8) [after
//   S1,S2(t) issue, outstanding = S3,S4(t-1)+S1,S2(t) = 8] + barrier.
//   F1'/F2' (kc0 of t+1, staged S3/S4(t-1)) retired by P4's vmcnt(4)
//   [outstanding after = S1,S2(t)] + barrier.
// WAR: S1/S2(t) overwrite [buf^1][1], whose readers (af1/bf1/ah1 of t-1)
//   retired before their consuming MFMAs, all before t-1 P4's lgkm0+barrier.
//   S3/S4(t) are POST-barrier: [buf][0] readers (af0/bf0 consumed P1, ah0
//   consumed P2) retired before each wave's P2/P3 bodies, hence before all
//   waves reach the P4 barrier. lgkm0 at P4 pins each wave's own in-flight
//   ds_reads (ah1/bf1) before the barrier so S1(t+1) cannot race them.
// Tail: stages guarded (S1,S2: t+1<NT; S3,S4: t+2<NT); P2 vmcnt = 8 if
//   t+1<NT else 0 (then outstanding = S1,S2(t-1) only); P4 sync skipped at
//   t = NT-1 (no next tile, no further LDS writes).
// ---------------------------------------------------------------------------
template <typename OutT>
__global__ __launch_bounds__(512, 2) void gemm256_kernel(
    const half_t* __restrict__ A, const half_t* __restrict__ Bt,
    const float* __restrict__ B0, const float* __restrict__ B1,
    const float* __restrict__ B2, OutT* __restrict__ C,
    int M, int N, int K) {
  __shared__ __align__(16) half_t As[2][2][256 * 32];   // [buf][kh] 16KB each
  __shared__ __align__(16) half_t Bs[2][2][256 * 32];

  const int tid = threadIdx.x;
  const int wave = tid >> 6, lane = tid & 63;
  const int r16 = lane & 15, quad = lane >> 4;
  const int wm = wave >> 2, wn = wave & 3;   // 2M x 4N wave grid

  // T1: XCD-chunked swizzle of linear block id (nwg % 8 == 0 for our grids)
  const int nbx = N >> 8;
  const int lid = (int)(blockIdx.y * gridDim.x + blockIdx.x);
  const int nwg = (int)(gridDim.x * gridDim.y);
  const int cpx = nwg >> 3;
  const int swz = (lid & 7) * cpx + (lid >> 3);
  const int brow = (swz / nbx) * 256;
  const int bcol = (swz % nbx) * 256;

  const int NT = K >> 6;   // K/64 tiles

  // half-tile stage: 256 rows x 32 halfs (64B/row), 1024 slots, 2/thread.
  // slot s: row=s>>2, LDS chunk s&3 holds global chunk (s&3)^((row>>1)&3).
  auto stA = [&](int t, int kh) {
    const int buf = t & 1;
    const int k0 = (t << 6) + (kh << 5);
#pragma unroll
    for (int j = 0; j < 2; ++j) {
      const int s = j * 512 + wave * 64 + lane;
      const int row = s >> 2;
      const int cg = (s & 3) ^ ((row >> 1) & 3);
      gll16(A + (size_t)(brow + row) * K + k0 + cg * 8,
            &As[buf][kh][(j * 512 + wave * 64) * 8]);
    }
  };
  auto stB = [&](int t, int kh) {
    const int buf = t & 1;
    const int k0 = (t << 6) + (kh << 5);
#pragma unroll
    for (int j = 0; j < 2; ++j) {
      const int s = j * 512 + wave * 64 + lane;
      const int row = s >> 2;
      const int cg = (s & 3) ^ ((row >> 1) & 3);
      gll16(Bt + (size_t)(bcol + row) * K + k0 + cg * 8,
            &Bs[buf][kh][(j * 512 + wave * 64) * 8]);
    }
  };

  f32x4 acc[8][4] = {};
  const int csw = (quad ^ ((r16 >> 1) & 3)) << 3;   // swizzled chunk (halfs)

  // prologue: kc0(0), kc1(0), kc0(1) = 12 loads; retire tile0 kc0 (vmcnt(8))
  stA(0, 0); stB(0, 0); stA(0, 1); stB(0, 1); stA(1, 0); stB(1, 0);
  asm volatile("s_waitcnt vmcnt(8)" ::: "memory");
  __builtin_amdgcn_s_barrier();
  __builtin_amdgcn_sched_barrier(0);

  f16x8 af0[4], bf0[4], ah0[4], af1[4], bf1[4], ah1[4];
  {
    const half_t* Ak0 = &As[0][0][0];
    const half_t* Bk0 = &Bs[0][0][0];
#pragma unroll
    for (int mi = 0; mi < 4; ++mi)
      af0[mi] = *reinterpret_cast<const f16x8*>(
          &Ak0[(wm * 128 + mi * 16 + r16) * 32 + csw]);
#pragma unroll
    for (int ni = 0; ni < 4; ++ni)
      bf0[ni] = *reinterpret_cast<const f16x8*>(
          &Bk0[(wn * 64 + ni * 16 + r16) * 32 + csw]);
  }

  for (int t = 0; t < NT; ++t) {
    const int buf = t & 1;
    const half_t* Ak0 = &As[buf][0][0];
    const half_t* Ak1 = &As[buf][1][0];
    const half_t* Bk1 = &Bs[buf][1][0];
    const half_t* An0 = &As[buf ^ 1][0][0];
    const half_t* Bn0 = &Bs[buf ^ 1][0][0];

    // ---- P1: read ah0 (next phase) || MFMA af0 x bf0 ----
#pragma unroll
    for (int mi = 0; mi < 4; ++mi)
      ah0[mi] = *reinterpret_cast<const f16x8*>(
          &Ak0[(wm * 128 + 64 + mi * 16 + r16) * 32 + csw]);
#pragma unroll
    for (int mi = 0; mi < 4; ++mi)
#pragma unroll
      for (int ni = 0; ni < 4; ++ni)
        acc[mi][ni] = __builtin_amdgcn_mfma_f32_16x16x32_f16(
            af0[mi], bf0[ni], acc[mi][ni], 0, 0, 0);

    // ---- P2: stage S1,S2 ; vmcnt ; barrier ; read af1 || MFMA ah0 x bf0 ----
    if (t + 1 < NT) {
      stA(t + 1, 1); stB(t + 1, 1);
      asm volatile("s_waitcnt vmcnt(8)" ::: "memory");
    } else {
      asm volatile("s_waitcnt vmcnt(0)" ::: "memory");
    }
    __builtin_amdgcn_s_barrier();
    __builtin_amdgcn_sched_barrier(0);
#pragma unroll
    for (int mi = 0; mi < 4; ++mi)
      af1[mi] = *reinterpret_cast<const f16x8*>(
          &Ak1[(wm * 128 + mi * 16 + r16) * 32 + csw]);
#pragma unroll
    for (int mi = 0; mi < 4; ++mi)
#pragma unroll
      for (int ni = 0; ni < 4; ++ni)
        acc[mi + 4][ni] = __builtin_amdgcn_mfma_f32_16x16x32_f16(
            ah0[mi], bf0[ni], acc[mi + 4][ni], 0, 0, 0);

    // ---- P3: read bf1, ah1 || MFMA af1 x bf1 ----
#pragma unroll
    for (int ni = 0; ni < 4; ++ni)
      bf1[ni] = *reinterpret_cast<const f16x8*>(
          &Bk1[(wn * 64 + ni * 16 + r16) * 32 + csw]);
#pragma unroll
    for (int mi = 0; mi < 4; ++mi)
      ah1[mi] = *reinterpret_cast<const f16x8*>(
          &Ak1[(wm * 128 + 64 + mi * 16 + r16) * 32 + csw]);
#pragma unroll
    for (int mi = 0; mi < 4; ++mi)
#pragma unroll
      for (int ni = 0; ni < 4; ++ni)
        acc[mi][ni] = __builtin_amdgcn_mfma_f32_16x16x32_f16(
            af1[mi], bf1[ni], acc[mi][ni], 0, 0, 0);

    // ---- P4: lgkm0+vmcnt(4) ; barrier ; stage S3,S4 ; read next-tile kc0
    //          || MFMA ah1 x bf1 ----
    if (t + 1 < NT) {
      asm volatile("s_waitcnt vmcnt(4) lgkmcnt(0)" ::: "memory");
      __builtin_amdgcn_s_barrier();
      __builtin_amdgcn_sched_barrier(0);
      if (t + 2 < NT) { stA(t + 2, 0); stB(t + 2, 0); }
#pragma unroll
      for (int mi = 0; mi < 4; ++mi)
        af0[mi] = *reinterpret_cast<const f16x8*>(
            &An0[(wm * 128 + mi * 16 + r16) * 32 + csw]);
#pragma unroll
      for (int ni = 0; ni < 4; ++ni)
        bf0[ni] = *reinterpret_cast<const f16x8*>(
            &Bn0[(wn * 64 + ni * 16 + r16) * 32 + csw]);
    }
#pragma unroll
    for (int mi = 0; mi < 4; ++mi)
#pragma unroll
      for (int ni = 0; ni < 4; ++ni)
        acc[mi + 4][ni] = __builtin_amdgcn_mfma_f32_16x16x32_f16(
            ah1[mi], bf1[ni], acc[mi + 4][ni], 0, 0, 0);
  }

  // epilogue: D row = (lane>>4)*4 + reg, col = lane&15 (verified C/D layout)
#pragma unroll
  for (int ni = 0; ni < 4; ++ni) {
    const int col = bcol + wn * 64 + ni * 16 + r16;
    float bv = 0.0f;
    if (B0) bv = (col < ND) ? B0[col]
                            : (col < ND + NKV * NHD ? B1[col - ND]
                                                    : B2[col - ND - NKV * NHD]);
#pragma unroll
    for (int mi = 0; mi < 8; ++mi) {
      const int row0 = brow + wm * 128 + mi * 16 + quad * 4;
#pragma unroll
      for (int i = 0; i < 4; ++i)
        C[(size_t)(row0 + i) * N + col] = (OutT)(acc[mi][ni][i] + bv);
    }
  }
}

// ---------------------------------------------------------------------------
// RoPE (half-split) + reshape for Q and K from merged raw fp16 [B*L, 6144].
// hp<32: Q head hp (QK_SCALE folded); else K head hp-32.
// ---------------------------------------------------------------------------
__global__ void ropepack_kernel(const half_t* __restrict__ rawh,
                                half_t* __restrict__ qb,
                                half_t* __restrict__ kb) {
  const size_t idx = (size_t)blockIdx.x * 256 + threadIdx.x;
  const int d = (int)(idx & 63);
  size_t t = idx >> 6;
  const int hp = (int)(t % (NH + NKV)); t /= (NH + NKV);
  const int l = (int)(t % NL);
  const int b = (int)(t / NL);
  const bool isQ = hp < NH;
  const int col0 = isQ ? hp * NHD : ND + (hp - NH) * NHD;
  const half_t* src = rawh + ((size_t)b * NL + l) * NQKV + col0;
  const float x1 = (float)src[d];
  const float x2 = (float)src[d + 64];
  const float inv_freq = exp2f(-(float)d * 0.20762050593045935f);
  const float ang = (float)l * inv_freq;
  float sn, cs;
  __sincosf(ang, &sn, &cs);
  const float scale = isQ ? QK_SCALE : 1.0f;
  half_t* dst = isQ ? qb + ((size_t)(b * NH + hp) * NL + l) * NHD
                    : kb + ((size_t)(b * NKV + (hp - NH)) * NL + l) * NHD;
  dst[d]      = (half_t)((x1 * cs - x2 * sn) * scale);
  dst[d + 64] = (half_t)((x2 * cs + x1 * sn) * scale);
}

// ---------------------------------------------------------------------------
// V: merged raw fp16 cols [5120,6144) -> Vt [B, KV, HD, L] fp16 (transpose)
// ---------------------------------------------------------------------------
__global__ void vtrans16_kernel(const half_t* __restrict__ rawh,
                                half_t* __restrict__ Vt) {
  __shared__ half_t tile[32][34];
  const int bkv = blockIdx.z;
  const int l0 = blockIdx.x * 32;
  const int d0 = blockIdx.y * 32;
  const int b = bkv / NKV, kvh = bkv % NKV;
  const int tx = threadIdx.x, ty = threadIdx.y;   // block (32,8)
#pragma unroll
  for (int r = 0; r < 32; r += 8)
    tile[ty + r][tx] = rawh[(size_t)(b * NL + l0 + ty + r) * NQKV
                            + ND + NKV * NHD + kvh * NHD + d0 + tx];
  __syncthreads();
  half_t* dst = Vt + (size_t)bkv * NHD * NL;
#pragma unroll
  for (int r = 0; r < 32; r += 8)
    dst[(size_t)(d0 + ty + r) * NL + l0 + tx] = tile[tx][ty + r];
}

// ---------------------------------------------------------------------------
// Flash attention (non-causal, GQA). 8 waves x 32 Q-rows = 256 rows/block.
// K/V tiles (64 keys) LDS-staged via global_load_lds, double-buffered,
// XOR chunk-swizzled. Softmax: fixed reference M0 (no per-tile max reduce),
// per-lane deferred row-sum (one reduce in epilogue), rare wave-uniform
// fallback rescale keeps arbitrary-data correctness.
// ---------------------------------------------------------------------------
#define KVB 64

__global__ __launch_bounds__(512, 2) void attn_kernel(
    const half_t* __restrict__ Q,   // [B,H,L,HD] scaled
    const half_t* __restrict__ Kh,  // [B,KV,L,HD]
    const half_t* __restrict__ Vt,  // [B,KV,HD,L]
    half_t* __restrict__ O) {
  __shared__ half_t Ks[2][KVB * NHD];   // 2 x 16KB
  __shared__ half_t Vs[2][NHD * KVB];   // 2 x 16KB
  __shared__ half_t Ps[8][16 * 64];     // 16KB, per-wave P tile

  const int tid = threadIdx.x;
  const int wave = tid >> 6, lane = tid & 63;
  const int r16 = lane & 15, quad = lane >> 4;
  const int r7 = r16 & 7;

  // XCD-chunked swizzle: 64 consecutive work-items per XCD (512 = 8*64)
  const int bid = (int)blockIdx.x;
  const int swz = (bid & 7) * 64 + (bid >> 3);
  const int nqt = NL / 256;                    // 8
  const int bh = swz / nqt, qt = swz % nqt;
  const int b = bh / NH, h = bh % NH;
  const int kvh = h / NG;

  const int qrow0 = qt * 256 + wave * 32;
  const half_t* Qb = Q  + ((size_t)(b * NH + h) * NL + qrow0) * NHD;
  const half_t* Kb = Kh + ((size_t)(b * NKV + kvh) * NL) * NHD;
  const half_t* Vb = Vt + ((size_t)(b * NKV + kvh) * NHD) * NL;
  half_t* Pw = &Ps[wave][0];

  // ---- stage(buf, n0): K tile 1024 slots, V tile 1024 slots (16B each) ----
  auto stage = [&](int buf, int n0) {
#pragma unroll
    for (int j = 0; j < 2; ++j) {
      const int slot = j * 512 + wave * 64 + lane;
      {
        const int row = slot >> 4;                    // key row 0..63
        const int c = (slot & 15) ^ (row & 7);        // global chunk
        gll16(Kb + (size_t)(n0 + row) * NHD + c * 8,
              &Ks[buf][(j * 512 + wave * 64) * 8]);
      }
      {
        const int row = slot >> 3;                    // d row 0..127
        const int c = (slot & 7) ^ (row & 7);
        gll16(Vb + (size_t)row * NL + n0 + c * 8,
              &Vs[buf][(j * 512 + wave * 64) * 8]);
      }
    }
  };

  stage(0, 0);

  // Q fragments: 2 row-tiles x 4 k-chunks
  f16x8 qf[2][4];
#pragma unroll
  for (int rt = 0; rt < 2; ++rt)
#pragma unroll
    for (int c = 0; c < 4; ++c)
      qf[rt][c] = *reinterpret_cast<const f16x8*>(
          &Qb[(size_t)(rt * 16 + r16) * NHD + c * 32 + quad * 8]);

  f32x4 oacc[2][8];
  float m_run[2][4], lsum[2][4];
#pragma unroll
  for (int rt = 0; rt < 2; ++rt) {
#pragma unroll
    for (int i = 0; i < 4; ++i) { m_run[rt][i] = M0; lsum[rt][i] = 0.0f; }
#pragma unroll
    for (int dt = 0; dt < 8; ++dt) oacc[rt][dt] = (f32x4){0.f, 0.f, 0.f, 0.f};
  }

  // P read swizzle (row = r16): mask = (r16&7) ^ ((r16>>3)*5)
  const int swzread = r7 ^ ((r16 >> 3) * 5);

  asm volatile("s_waitcnt vmcnt(0)" ::: "memory");
  __syncthreads();

  int cur = 0;
  for (int t = 0; t < NL / KVB; ++t, cur ^= 1) {
    if (t + 1 < NL / KVB) stage(cur ^ 1, (t + 1) * KVB);

    const half_t* Kc = &Ks[cur][0];
    const half_t* Vc = &Vs[cur][0];

    // ---- S = Q K^T (swizzled K reads) ----
    f32x4 s[2][4] = {};
#pragma unroll
    for (int c = 0; c < 4; ++c) {
      const int ch = ((c * 4 + quad) ^ r7) * 8;
#pragma unroll
      for (int nt = 0; nt < 4; ++nt) {
        f16x8 kf = *reinterpret_cast<const f16x8*>(&Kc[(nt * 16 + r16) * NHD + ch]);
        s[0][nt] = __builtin_amdgcn_mfma_f32_16x16x32_f16(qf[0][c], kf, s[0][nt], 0, 0, 0);
        s[1][nt] = __builtin_amdgcn_mfma_f32_16x16x32_f16(qf[1][c], kf, s[1][nt], 0, 0, 0);
      }
    }

    // ---- fallback check: any lane-local score above M0+THR? (no reduce) ----
    float mx[2][4];
    bool need = false;
#pragma unroll
    for (int rt = 0; rt < 2; ++rt)
#pragma unroll
      for (int i = 0; i < 4; ++i) {
        mx[rt][i] = fmaxf(fmaxf(s[rt][0][i], s[rt][1][i]),
                          fmaxf(s[rt][2][i], s[rt][3][i]));
        need = need || (mx[rt][i] > m_run[rt][i] + THR);
      }
    if (__any(need ? 1 : 0)) {   // rare: full reduce + rescale (correctness)
#pragma unroll
      for (int rt = 0; rt < 2; ++rt)
#pragma unroll
        for (int i = 0; i < 4; ++i) {
          float m = mx[rt][i];
#pragma unroll
          for (int off = 1; off < 16; off <<= 1)
            m = fmaxf(m, __shfl_xor(m, off));
          const float mn = fmaxf(m_run[rt][i], m);
          const float corr = exp2f((m_run[rt][i] - mn) * RLOG2E);
          m_run[rt][i] = mn;
          lsum[rt][i] *= corr;
#pragma unroll
          for (int dt = 0; dt < 8; ++dt) oacc[rt][dt][i] *= corr;
        }
    }

    // ---- P = exp(S - m), per-lane partial sums, swizzled LDS writes ----
    f16x8 pa[2][2];
#pragma unroll
    for (int rt = 0; rt < 2; ++rt) {
#pragma unroll
      for (int i = 0; i < 4; ++i) {
        const float mrl = m_run[rt][i] * RLOG2E;
        float p[4];
#pragma unroll
        for (int nt = 0; nt < 4; ++nt)
          p[nt] = exp2f(s[rt][nt][i] * RLOG2E - mrl);
        lsum[rt][i] += (p[0] + p[1]) + (p[2] + p[3]);
        const int row = quad * 4 + i;
        const int swzr = (row & 7) ^ ((row >> 3) * 5);
#pragma unroll
        for (int nt = 0; nt < 4; ++nt)
          Pw[row * 64 + (((nt * 2 + (r16 >> 3)) ^ swzr) * 8) + r7] = (half_t)p[nt];
      }
      // A-fragments (wave-private LDS; in-order DS pipe, no barrier)
      pa[rt][0] = *reinterpret_cast<const f16x8*>(&Pw[r16 * 64 + ((quad ^ swzread) * 8)]);
      pa[rt][1] = *reinterpret_cast<const f16x8*>(&Pw[r16 * 64 + (((4 + quad) ^ swzread) * 8)]);
    }

    // ---- O += P V (swizzled V reads, shared across both row-tiles) ----
    const int ch0 = (quad ^ r7) * 8;
    const int ch1 = ((4 + quad) ^ r7) * 8;
#pragma unroll
    for (int dt = 0; dt < 8; ++dt) {
      const int row = dt * 16 + r16;
      f16x8 v0 = *reinterpret_cast<const f16x8*>(&Vc[row * 64 + ch0]);
      f16x8 v1 = *reinterpret_cast<const f16x8*>(&Vc[row * 64 + ch1]);
      oacc[0][dt] = __builtin_amdgcn_mfma_f32_16x16x32_f16(pa[0][0], v0, oacc[0][dt], 0, 0, 0);
      oacc[0][dt] = __builtin_amdgcn_mfma_f32_16x16x32_f16(pa[0][1], v1, oacc[0][dt], 0, 0, 0);
      oacc[1][dt] = __builtin_amdgcn_mfma_f32_16x16x32_f16(pa[1][0], v0, oacc[1][dt], 0, 0, 0);
      oacc[1][dt] = __builtin_amdgcn_mfma_f32_16x16x32_f16(pa[1][1], v1, oacc[1][dt], 0, 0, 0);
    }

    asm volatile("s_waitcnt vmcnt(0)" ::: "memory");
    __syncthreads();
  }

  // ---- epilogue: one deferred row-sum reduce, normalize, write fp16 ----
  half_t* Ob = O + ((size_t)(b * NL) + qrow0) * (NH * NHD) + (size_t)h * NHD;
#pragma unroll
  for (int rt = 0; rt < 2; ++rt)
#pragma unroll
    for (int i = 0; i < 4; ++i) {
      float l = lsum[rt][i];
#pragma unroll
      for (int off = 1; off < 16; off <<= 1)
        l += __shfl_xor(l, off);
      const float inv = 1.0f / l;
      const int rl = rt * 16 + quad * 4 + i;
#pragma unroll
      for (int dt = 0; dt < 8; ++dt)
        Ob[(size_t)rl * (NH * NHD) + dt * 16 + r16] =
            (half_t)(oacc[rt][dt][i] * inv);
    }
}

// ---------------------------------------------------------------------------
extern "C" void kernel_launch(void* const* d_in, const int* in_sizes, int n_in,
                              void* d_out, int out_size, void* d_ws, size_t ws_size,
                              hipStream_t stream) {
  const float* x  = (const float*)d_in[0];
  const float* Wq = (const float*)d_in[1];
  const float* bq = (const float*)d_in[2];
  const float* Wk = (const float*)d_in[3];
  const float* bk = (const float*)d_in[4];
  const float* Wv = (const float*)d_in[5];
  const float* bv = (const float*)d_in[6];
  const float* Wo = (const float*)d_in[7];
  float* out = (float*)d_out;

  char* ws = (char*)d_ws;
  size_t off = 0;
  auto alloc = [&](size_t bytes) {
    size_t cur = off;
    off += (bytes + 255) & ~(size_t)255;
    return cur;
  };
  const size_t M = (size_t)NB * NL;  // 4096 token rows
  // buffer plan (~185 MB):
  half_t* xb   = (half_t*)(ws + alloc(M * ND * 2));            // x fp16; reused as AttnOut
  half_t* wqkv = (half_t*)(ws + alloc((size_t)NQKV * ND * 2)); // [Wq;Wk;Wv]^T; reused for Wo^T
  half_t* rawh = (half_t*)(ws + alloc(M * NQKV * 2));          // merged QKV raw fp16
  half_t* qb   = (half_t*)(ws + alloc(M * (size_t)(NH * NHD) * 2));
  half_t* kb   = (half_t*)(ws + alloc(M * (size_t)(NKV * NHD) * 2));
  half_t* vt   = (half_t*)(ws + alloc(M * (size_t)(NKV * NHD) * 2));

  // 1) x -> fp16
  {
    int n4 = (int)(M * ND / 4);
    convert_f32_f16_kernel<<<dim3((n4 + 255) / 256), dim3(256), 0, stream>>>(x, xb, n4);
  }
  // 2) weight transposes into merged [6144][4096] fp16
  wtrans_kernel<<<dim3(ND / 32, ND / 32), dim3(32, 8), 0, stream>>>(
      Wq, wqkv, ND, ND);
  wtrans_kernel<<<dim3((NKV * NHD) / 32, ND / 32), dim3(32, 8), 0, stream>>>(
      Wk, wqkv + (size_t)ND * ND, ND, NKV * NHD);
  wtrans_kernel<<<dim3((NKV * NHD) / 32, ND / 32), dim3(32, 8), 0, stream>>>(
      Wv, wqkv + (size_t)(ND + NKV * NHD) * ND, ND, NKV * NHD);

  // 3) merged QKV GEMM -> rawh fp16 (bias fused, 3-way select)
  gemm256_kernel<half_t><<<dim3(NQKV / 256, M / 256), dim3(512), 0, stream>>>(
      xb, wqkv, bq, bk, bv, rawh, (int)M, NQKV, ND);

  // 4) RoPE+pack Q,K; transpose V
  ropepack_kernel<<<dim3((unsigned)(M * (NH + NKV) * 64 / 256)), dim3(256), 0, stream>>>(
      rawh, qb, kb);
  vtrans16_kernel<<<dim3(NL / 32, NHD / 32, NB * NKV), dim3(32, 8), 0, stream>>>(rawh, vt);

  // 5) Wo^T into wqkv (dead after step 3; stream order guarantees safety)
  wtrans_kernel<<<dim3(ND / 32, ND / 32), dim3(32, 8), 0, stream>>>(Wo, wqkv, NH * NHD, ND);

  // 6) attention -> xb (reused as AttnOut, [B*L, H*HD] fp16)
  attn_kernel<<<dim3(NB * NH * (NL / 256)), dim3(512), 0, stream>>>(qb, kb, vt, xb);

  // 7) output projection -> d_out (fp32)
  gemm256_kernel<float><<<dim3(ND / 256, M / 256), dim3(512), 0, stream>>>(
      xb, wqkv, nullptr, nullptr, nullptr, out, (int)M, ND, ND);
}

// Round 10
// 674.634 us; speedup vs baseline: 1.0489x; 1.0479x over previous
//
#include <hip/hip_runtime.h>
#include <stdint.h>
#include <stddef.h>

// ---------------------------------------------------------------------------
// Fused GQA attention block: QKV proj + half-split RoPE + flash attention +
// output proj. fp16 MFMA (16x16x32) everywhere, fp32 accumulate/softmax.
// R10: GEMM reverted to R7 (best measured: 8-phase lockstep, counted vmcnt,
// conflict-free swizzle). Attn: + setprio around MFMA clusters (T5).
// RoPE: host-free sin/cos table kernel (1MB, L2-resident) replaces per-thread
// exp2f+sincosf in ropepack (m205: on-device trig on memory-bound op).
// ---------------------------------------------------------------------------

typedef _Float16 half_t;
typedef __attribute__((ext_vector_type(4))) _Float16 f16x4;
typedef __attribute__((ext_vector_type(8))) _Float16 f16x8;
typedef __attribute__((ext_vector_type(4))) float f32x4;

#define NB 2
#define NL 2048
#define ND 4096
#define NH 32
#define NKV 8
#define NHD 128
#define NG 4               // H / KV
#define NQKV 6144          // H*HD + 2*KV*HD
#define QK_SCALE 0.08838834764831845f   // HD^-0.5
#define RLOG2E 1.4426950408889634f
#define M0 6.0f            // fixed softmax reference (scores ~N(0,1.64^2))
#define THR 8.0f           // defer-max threshold (fallback if mx > M0+THR)

// async global->LDS, 16B per lane. LDS dest must be wave-uniform base;
// lane i lands at base + i*16 (HW-defined linear scatter).
static __device__ __forceinline__ void gll16(const void* g, void* l) {
  __builtin_amdgcn_global_load_lds(
      (__attribute__((address_space(1))) void*)(void*)(g),
      (__attribute__((address_space(3))) void*)(l),
      16, 0, 0);
}

// ---------------------------------------------------------------------------
// elementwise fp32 -> fp16 (vectorized: float4 in, 4xfp16 out)
// ---------------------------------------------------------------------------
__global__ void convert_f32_f16_kernel(const float* __restrict__ in,
                                       half_t* __restrict__ out, int n4) {
  int i = blockIdx.x * 256 + threadIdx.x;
  if (i >= n4) return;
  const float4 v = reinterpret_cast<const float4*>(in)[i];
  f16x4 o;
  o[0] = (half_t)v.x; o[1] = (half_t)v.y; o[2] = (half_t)v.z; o[3] = (half_t)v.w;
  reinterpret_cast<f16x4*>(out)[i] = o;
}

// ---------------------------------------------------------------------------
// W [K,N] fp32 row-major  ->  Wt [N,K] fp16 row-major (LDS 32x32 tile transpose)
// ---------------------------------------------------------------------------
__global__ void wtrans_kernel(const float* __restrict__ W,
                              half_t* __restrict__ Wt, int K, int N) {
  __shared__ float tile[32][33];
  const int n0 = blockIdx.x * 32;
  const int k0 = blockIdx.y * 32;
  const int tx = threadIdx.x, ty = threadIdx.y;   // block (32,8)
#pragma unroll
  for (int r = 0; r < 32; r += 8)
    tile[ty + r][tx] = W[(size_t)(k0 + ty + r) * N + n0 + tx];
  __syncthreads();
#pragma unroll
  for (int r = 0; r < 32; r += 8)
    Wt[(size_t)(n0 + ty + r) * K + k0 + tx] = (half_t)tile[tx][ty + r];
}

// ---------------------------------------------------------------------------
// RoPE sin/cos table: tab[l*64+d] = {cos(l*invfreq(d)), sin(l*invfreq(d))}
// ---------------------------------------------------------------------------
__global__ void ropetab_kernel(float2* __restrict__ tab) {
  const int idx = blockIdx.x * 256 + threadIdx.x;   // NL*64 entries
  const int d = idx & 63;
  const int l = idx >> 6;
  const float inv_freq = exp2f(-(float)d * 0.20762050593045935f);
  const float ang = (float)l * inv_freq;
  float sn, cs;
  __sincosf(ang, &sn, &cs);
  tab[idx] = make_float2(cs, sn);
}

// ---------------------------------------------------------------------------
// GEMM: C[M,N] = A[M,K] * Bt[N,K]^T (+ 3-way bias), A/Bt fp16, C fp32/fp16.
// 256x256 tile, 8 waves (2M x 4N, each 128x64 out), BK=64 as 2 K-halves.
// LDS [2buf][2kh][256 rows][32 halfs] per array (128 KB total).
// Per K-tile t (buf=t&1), 4 phases x 16 MFMA; each phase: {ds_reads; stage
// ONE half-tile; [vmcnt]; barrier; lgkm0; setprio1; MFMA x16; setprio0;
// barrier}. Stage targets / waits (steady state 12 loads in flight):
//   P1: stage A(t+1)kc1            (slot free since P4(t-1) barrier)
//   P2: stage B(t+1)kc1; vmcnt(8)  -> retires A(t)kc1,B(t)kc1 for P3 reads
//   P3: stage A(t+2)kc0            (free after P2 barrier: kc0 fully read)
//   P4: stage B(t+2)kc0; vmcnt(8)  -> retires A(t+1)kc0,B(t+1)kc0 for next P1
// RAW: every half is vmcnt-retired >=1 phase before its ds_read, with a
// barrier in between (block-wide residency). WAR: every stage slot's last
// reader finished before the preceding phase-end barrier.
// Swizzle: global chunk cg stored at LDS chunk cg^((row>>1)&3); reads use
// csw = (quad ^ ((r16>>1)&3)) -> measured 0 bank conflicts.
// ---------------------------------------------------------------------------
template <typename OutT>
__global__ __launch_bounds__(512, 2) void gemm256_kernel(
    const half_t* __restrict__ A, const half_t* __restrict__ Bt,
    const float* __restrict__ B0, const float* __restrict__ B1,
    const float* __restrict__ B2, OutT* __restrict__ C,
    int M, int N, int K) {
  __shared__ __align__(16) half_t As[2][2][256 * 32];   // [buf][kh] 16KB each
  __shared__ __align__(16) half_t Bs[2][2][256 * 32];

  const int tid = threadIdx.x;
  const int wave = tid >> 6, lane = tid & 63;
  const int r16 = lane & 15, quad = lane >> 4;
  const int wm = wave >> 2, wn = wave & 3;   // 2M x 4N wave grid

  // T1: XCD-chunked swizzle of linear block id (nwg % 8 == 0 for our grids)
  const int nbx = N >> 8;
  const int lid = (int)(blockIdx.y * gridDim.x + blockIdx.x);
  const int nwg = (int)(gridDim.x * gridDim.y);
  const int cpx = nwg >> 3;
  const int swz = (lid & 7) * cpx + (lid >> 3);
  const int brow = (swz / nbx) * 256;
  const int bcol = (swz % nbx) * 256;

  const int NT = K >> 6;   // K/64 tiles

  // half-tile stage: 256 rows x 32 halfs (64B/row), 1024 slots, 2/thread.
  // slot s: row=s>>2, LDS chunk s&3 holds global chunk (s&3)^((row>>1)&3).
  auto stA = [&](int t, int kh) {
    const int buf = t & 1;
    const int k0 = (t << 6) + (kh << 5);
#pragma unroll
    for (int j = 0; j < 2; ++j) {
      const int s = j * 512 + wave * 64 + lane;
      const int row = s >> 2;
      const int cg = (s & 3) ^ ((row >> 1) & 3);
      gll16(A + (size_t)(brow + row) * K + k0 + cg * 8,
            &As[buf][kh][(j * 512 + wave * 64) * 8]);
    }
  };
  auto stB = [&](int t, int kh) {
    const int buf = t & 1;
    const int k0 = (t << 6) + (kh << 5);
#pragma unroll
    for (int j = 0; j < 2; ++j) {
      const int s = j * 512 + wave * 64 + lane;
      const int row = s >> 2;
      const int cg = (s & 3) ^ ((row >> 1) & 3);
      gll16(Bt + (size_t)(bcol + row) * K + k0 + cg * 8,
            &Bs[buf][kh][(j * 512 + wave * 64) * 8]);
    }
  };

  f32x4 acc[8][4] = {};
  const int csw = (quad ^ ((r16 >> 1) & 3)) << 3;   // swizzled chunk (halfs)

  // prologue: A0kc0,B0kc0,A0kc1,B0kc1,A1kc0,B1kc0 (12 loads); retire tile0 kc0
  stA(0, 0); stB(0, 0); stA(0, 1); stB(0, 1); stA(1, 0); stB(1, 0);
  asm volatile("s_waitcnt vmcnt(8)" ::: "memory");
  __builtin_amdgcn_s_barrier();

  for (int t = 0; t < NT; ++t) {
    const int buf = t & 1;
    const half_t* Ak0 = &As[buf][0][0];
    const half_t* Ak1 = &As[buf][1][0];
    const half_t* Bk0 = &Bs[buf][0][0];
    const half_t* Bk1 = &Bs[buf][1][0];
    f16x8 af[4], bf[4], ah[4];

    // ================= P1: mi0-3 x ni0-3, kc0 =================
#pragma unroll
    for (int mi = 0; mi < 4; ++mi)
      af[mi] = *reinterpret_cast<const f16x8*>(
          &Ak0[(wm * 128 + mi * 16 + r16) * 32 + csw]);
#pragma unroll
    for (int ni = 0; ni < 4; ++ni)
      bf[ni] = *reinterpret_cast<const f16x8*>(
          &Bk0[(wn * 64 + ni * 16 + r16) * 32 + csw]);
    if (t + 1 < NT) stA(t + 1, 1);
    __builtin_amdgcn_sched_barrier(0);
    __builtin_amdgcn_s_barrier();
    asm volatile("s_waitcnt lgkmcnt(0)" ::: "memory");
    __builtin_amdgcn_sched_barrier(0);
    __builtin_amdgcn_s_setprio(1);
#pragma unroll
    for (int mi = 0; mi < 4; ++mi)
#pragma unroll
      for (int ni = 0; ni < 4; ++ni)
        acc[mi][ni] = __builtin_amdgcn_mfma_f32_16x16x32_f16(
            af[mi], bf[ni], acc[mi][ni], 0, 0, 0);
    __builtin_amdgcn_s_setprio(0);
    __builtin_amdgcn_s_barrier();

    // ================= P2: mi4-7 x ni0-3, kc0 (reuse bf) =================
#pragma unroll
    for (int mi = 0; mi < 4; ++mi)
      ah[mi] = *reinterpret_cast<const f16x8*>(
          &Ak0[(wm * 128 + 64 + mi * 16 + r16) * 32 + csw]);
    if (t + 1 < NT) stB(t + 1, 1);
    if (t + 1 < NT) {
      asm volatile("s_waitcnt vmcnt(8)" ::: "memory");   // retire t:kc1 halves
    } else {
      asm volatile("s_waitcnt vmcnt(0)" ::: "memory");
    }
    __builtin_amdgcn_sched_barrier(0);
    __builtin_amdgcn_s_barrier();
    asm volatile("s_waitcnt lgkmcnt(0)" ::: "memory");
    __builtin_amdgcn_sched_barrier(0);
    __builtin_amdgcn_s_setprio(1);
#pragma unroll
    for (int mi = 0; mi < 4; ++mi)
#pragma unroll
      for (int ni = 0; ni < 4; ++ni)
        acc[mi + 4][ni] = __builtin_amdgcn_mfma_f32_16x16x32_f16(
            ah[mi], bf[ni], acc[mi + 4][ni], 0, 0, 0);
    __builtin_amdgcn_s_setprio(0);
    __builtin_amdgcn_s_barrier();

    // ================= P3: mi0-3 x ni0-3, kc1 =================
#pragma unroll
    for (int mi = 0; mi < 4; ++mi)
      af[mi] = *reinterpret_cast<const f16x8*>(
          &Ak1[(wm * 128 + mi * 16 + r16) * 32 + csw]);
#pragma unroll
    for (int ni = 0; ni < 4; ++ni)
      bf[ni] = *reinterpret_cast<const f16x8*>(
          &Bk1[(wn * 64 + ni * 16 + r16) * 32 + csw]);
    if (t + 2 < NT) stA(t + 2, 0);
    __builtin_amdgcn_sched_barrier(0);
    __builtin_amdgcn_s_barrier();
    asm volatile("s_waitcnt lgkmcnt(0)" ::: "memory");
    __builtin_amdgcn_sched_barrier(0);
    __builtin_amdgcn_s_setprio(1);
#pragma unroll
    for (int mi = 0; mi < 4; ++mi)
#pragma unroll
      for (int ni = 0; ni < 4; ++ni)
        acc[mi][ni] = __builtin_amdgcn_mfma_f32_16x16x32_f16(
            af[mi], bf[ni], acc[mi][ni], 0, 0, 0);
    __builtin_amdgcn_s_setprio(0);
    __builtin_amdgcn_s_barrier();

    // ================= P4: mi4-7 x ni0-3, kc1 (reuse bf) =================
#pragma unroll
    for (int mi = 0; mi < 4; ++mi)
      ah[mi] = *reinterpret_cast<const f16x8*>(
          &Ak1[(wm * 128 + 64 + mi * 16 + r16) * 32 + csw]);
    if (t + 2 < NT) stB(t + 2, 0);
    if (t + 2 < NT) {
      asm volatile("s_waitcnt vmcnt(8)" ::: "memory");   // retire t+1:kc0
    } else if (t + 1 < NT) {
      asm volatile("s_waitcnt vmcnt(4)" ::: "memory");
    } else {
      asm volatile("s_waitcnt vmcnt(0)" ::: "memory");
    }
    __builtin_amdgcn_sched_barrier(0);
    __builtin_amdgcn_s_barrier();
    asm volatile("s_waitcnt lgkmcnt(0)" ::: "memory");
    __builtin_amdgcn_sched_barrier(0);
    __builtin_amdgcn_s_setprio(1);
#pragma unroll
    for (int mi = 0; mi < 4; ++mi)
#pragma unroll
      for (int ni = 0; ni < 4; ++ni)
        acc[mi + 4][ni] = __builtin_amdgcn_mfma_f32_16x16x32_f16(
            ah[mi], bf[ni], acc[mi + 4][ni], 0, 0, 0);
    __builtin_amdgcn_s_setprio(0);
    __builtin_amdgcn_s_barrier();
  }

  // epilogue: D row = (lane>>4)*4 + reg, col = lane&15 (verified C/D layout)
#pragma unroll
  for (int ni = 0; ni < 4; ++ni) {
    const int col = bcol + wn * 64 + ni * 16 + r16;
    float bv = 0.0f;
    if (B0) bv = (col < ND) ? B0[col]
                            : (col < ND + NKV * NHD ? B1[col - ND]
                                                    : B2[col - ND - NKV * NHD]);
#pragma unroll
    for (int mi = 0; mi < 8; ++mi) {
      const int row0 = brow + wm * 128 + mi * 16 + quad * 4;
#pragma unroll
      for (int i = 0; i < 4; ++i)
        C[(size_t)(row0 + i) * N + col] = (OutT)(acc[mi][ni][i] + bv);
    }
  }
}

// ---------------------------------------------------------------------------
// RoPE (half-split, table-driven) + reshape for Q and K from merged raw fp16.
// hp<32: Q head hp (QK_SCALE folded); else K head hp-32.
// ---------------------------------------------------------------------------
__global__ void ropepack_kernel(const half_t* __restrict__ rawh,
                                const float2* __restrict__ tab,
                                half_t* __restrict__ qb,
                                half_t* __restrict__ kb) {
  const size_t idx = (size_t)blockIdx.x * 256 + threadIdx.x;
  const int d = (int)(idx & 63);
  size_t t = idx >> 6;
  const int hp = (int)(t % (NH + NKV)); t /= (NH + NKV);
  const int l = (int)(t % NL);
  const int b = (int)(t / NL);
  const bool isQ = hp < NH;
  const int col0 = isQ ? hp * NHD : ND + (hp - NH) * NHD;
  const half_t* src = rawh + ((size_t)b * NL + l) * NQKV + col0;
  const float x1 = (float)src[d];
  const float x2 = (float)src[d + 64];
  const float2 cssn = tab[(size_t)l * 64 + d];
  const float scale = isQ ? QK_SCALE : 1.0f;
  half_t* dst = isQ ? qb + ((size_t)(b * NH + hp) * NL + l) * NHD
                    : kb + ((size_t)(b * NKV + (hp - NH)) * NL + l) * NHD;
  dst[d]      = (half_t)((x1 * cssn.x - x2 * cssn.y) * scale);
  dst[d + 64] = (half_t)((x2 * cssn.x + x1 * cssn.y) * scale);
}

// ---------------------------------------------------------------------------
// V: merged raw fp16 cols [5120,6144) -> Vt [B, KV, HD, L] fp16 (transpose)
// ---------------------------------------------------------------------------
__global__ void vtrans16_kernel(const half_t* __restrict__ rawh,
                                half_t* __restrict__ Vt) {
  __shared__ half_t tile[32][34];
  const int bkv = blockIdx.z;
  const int l0 = blockIdx.x * 32;
  const int d0 = blockIdx.y * 32;
  const int b = bkv / NKV, kvh = bkv % NKV;
  const int tx = threadIdx.x, ty = threadIdx.y;   // block (32,8)
#pragma unroll
  for (int r = 0; r < 32; r += 8)
    tile[ty + r][tx] = rawh[(size_t)(b * NL + l0 + ty + r) * NQKV
                            + ND + NKV * NHD + kvh * NHD + d0 + tx];
  __syncthreads();
  half_t* dst = Vt + (size_t)bkv * NHD * NL;
#pragma unroll
  for (int r = 0; r < 32; r += 8)
    dst[(size_t)(d0 + ty + r) * NL + l0 + tx] = tile[tx][ty + r];
}

// ---------------------------------------------------------------------------
// Flash attention (non-causal, GQA). 8 waves x 32 Q-rows = 256 rows/block.
// K/V tiles (64 keys) LDS-staged via global_load_lds, double-buffered,
// XOR chunk-swizzled. Softmax: fixed reference M0 (no per-tile max reduce),
// per-lane deferred row-sum (one reduce in epilogue), rare wave-uniform
// fallback rescale keeps arbitrary-data correctness. T5 setprio on MFMA.
// ---------------------------------------------------------------------------
#define KVB 64

__global__ __launch_bounds__(512, 2) void attn_kernel(
    const half_t* __restrict__ Q,   // [B,H,L,HD] scaled
    const half_t* __restrict__ Kh,  // [B,KV,L,HD]
    const half_t* __restrict__ Vt,  // [B,KV,HD,L]
    half_t* __restrict__ O) {
  __shared__ half_t Ks[2][KVB * NHD];   // 2 x 16KB
  __shared__ half_t Vs[2][NHD * KVB];   // 2 x 16KB
  __shared__ half_t Ps[8][16 * 64];     // 16KB, per-wave P tile

  const int tid = threadIdx.x;
  const int wave = tid >> 6, lane = tid & 63;
  const int r16 = lane & 15, quad = lane >> 4;
  const int r7 = r16 & 7;

  // XCD-chunked swizzle: 64 consecutive work-items per XCD (512 = 8*64)
  const int bid = (int)blockIdx.x;
  const int swz = (bid & 7) * 64 + (bid >> 3);
  const int nqt = NL / 256;                    // 8
  const int bh = swz / nqt, qt = swz % nqt;
  const int b = bh / NH, h = bh % NH;
  const int kvh = h / NG;

  const int qrow0 = qt * 256 + wave * 32;
  const half_t* Qb = Q  + ((size_t)(b * NH + h) * NL + qrow0) * NHD;
  const half_t* Kb = Kh + ((size_t)(b * NKV + kvh) * NL) * NHD;
  const half_t* Vb = Vt + ((size_t)(b * NKV + kvh) * NHD) * NL;
  half_t* Pw = &Ps[wave][0];

  // ---- stage(buf, n0): K tile 1024 slots, V tile 1024 slots (16B each) ----
  auto stage = [&](int buf, int n0) {
#pragma unroll
    for (int j = 0; j < 2; ++j) {
      const int slot = j * 512 + wave * 64 + lane;
      {
        const int row = slot >> 4;                    // key row 0..63
        const int c = (slot & 15) ^ (row & 7);        // global chunk
        gll16(Kb + (size_t)(n0 + row) * NHD + c * 8,
              &Ks[buf][(j * 512 + wave * 64) * 8]);
      }
      {
        const int row = slot >> 3;                    // d row 0..127
        const int c = (slot & 7) ^ (row & 7);
        gll16(Vb + (size_t)row * NL + n0 + c * 8,
              &Vs[buf][(j * 512 + wave * 64) * 8]);
      }
    }
  };

  stage(0, 0);

  // Q fragments: 2 row-tiles x 4 k-chunks
  f16x8 qf[2][4];
#pragma unroll
  for (int rt = 0; rt < 2; ++rt)
#pragma unroll
    for (int c = 0; c < 4; ++c)
      qf[rt][c] = *reinterpret_cast<const f16x8*>(
          &Qb[(size_t)(rt * 16 + r16) * NHD + c * 32 + quad * 8]);

  f32x4 oacc[2][8];
  float m_run[2][4], lsum[2][4];
#pragma unroll
  for (int rt = 0; rt < 2; ++rt) {
#pragma unroll
    for (int i = 0; i < 4; ++i) { m_run[rt][i] = M0; lsum[rt][i] = 0.0f; }
#pragma unroll
    for (int dt = 0; dt < 8; ++dt) oacc[rt][dt] = (f32x4){0.f, 0.f, 0.f, 0.f};
  }

  // P read swizzle (row = r16): mask = (r16&7) ^ ((r16>>3)*5)
  const int swzread = r7 ^ ((r16 >> 3) * 5);

  asm volatile("s_waitcnt vmcnt(0)" ::: "memory");
  __syncthreads();

  int cur = 0;
  for (int t = 0; t < NL / KVB; ++t, cur ^= 1) {
    if (t + 1 < NL / KVB) stage(cur ^ 1, (t + 1) * KVB);

    const half_t* Kc = &Ks[cur][0];
    const half_t* Vc = &Vs[cur][0];

    // ---- S = Q K^T (swizzled K reads) ----
    f32x4 s[2][4] = {};
    __builtin_amdgcn_s_setprio(1);
#pragma unroll
    for (int c = 0; c < 4; ++c) {
      const int ch = ((c * 4 + quad) ^ r7) * 8;
#pragma unroll
      for (int nt = 0; nt < 4; ++nt) {
        f16x8 kf = *reinterpret_cast<const f16x8*>(&Kc[(nt * 16 + r16) * NHD + ch]);
        s[0][nt] = __builtin_amdgcn_mfma_f32_16x16x32_f16(qf[0][c], kf, s[0][nt], 0, 0, 0);
        s[1][nt] = __builtin_amdgcn_mfma_f32_16x16x32_f16(qf[1][c], kf, s[1][nt], 0, 0, 0);
      }
    }
    __builtin_amdgcn_s_setprio(0);

    // ---- fallback check: any lane-local score above M0+THR? (no reduce) ----
    float mx[2][4];
    bool need = false;
#pragma unroll
    for (int rt = 0; rt < 2; ++rt)
#pragma unroll
      for (int i = 0; i < 4; ++i) {
        mx[rt][i] = fmaxf(fmaxf(s[rt][0][i], s[rt][1][i]),
                          fmaxf(s[rt][2][i], s[rt][3][i]));
        need = need || (mx[rt][i] > m_run[rt][i] + THR);
      }
    if (__any(need ? 1 : 0)) {   // rare: full reduce + rescale (correctness)
#pragma unroll
      for (int rt = 0; rt < 2; ++rt)
#pragma unroll
        for (int i = 0; i < 4; ++i) {
          float m = mx[rt][i];
#pragma unroll
          for (int off = 1; off < 16; off <<= 1)
            m = fmaxf(m, __shfl_xor(m, off));
          const float mn = fmaxf(m_run[rt][i], m);
          const float corr = exp2f((m_run[rt][i] - mn) * RLOG2E);
          m_run[rt][i] = mn;
          lsum[rt][i] *= corr;
#pragma unroll
          for (int dt = 0; dt < 8; ++dt) oacc[rt][dt][i] *= corr;
        }
    }

    // ---- P = exp(S - m), per-lane partial sums, swizzled LDS writes ----
    f16x8 pa[2][2];
#pragma unroll
    for (int rt = 0; rt < 2; ++rt) {
#pragma unroll
      for (int i = 0; i < 4; ++i) {
        const float mrl = m_run[rt][i] * RLOG2E;
        float p[4];
#pragma unroll
        for (int nt = 0; nt < 4; ++nt)
          p[nt] = exp2f(s[rt][nt][i] * RLOG2E - mrl);
        lsum[rt][i] += (p[0] + p[1]) + (p[2] + p[3]);
        const int row = quad * 4 + i;
        const int swzr = (row & 7) ^ ((row >> 3) * 5);
#pragma unroll
        for (int nt = 0; nt < 4; ++nt)
          Pw[row * 64 + (((nt * 2 + (r16 >> 3)) ^ swzr) * 8) + r7] = (half_t)p[nt];
      }
      // A-fragments (wave-private LDS; in-order DS pipe, no barrier)
      pa[rt][0] = *reinterpret_cast<const f16x8*>(&Pw[r16 * 64 + ((quad ^ swzread) * 8)]);
      pa[rt][1] = *reinterpret_cast<const f16x8*>(&Pw[r16 * 64 + (((4 + quad) ^ swzread) * 8)]);
    }

    // ---- O += P V (swizzled V reads, shared across both row-tiles) ----
    const int ch0 = (quad ^ r7) * 8;
    const int ch1 = ((4 + quad) ^ r7) * 8;
    __builtin_amdgcn_s_setprio(1);
#pragma unroll
    for (int dt = 0; dt < 8; ++dt) {
      const int row = dt * 16 + r16;
      f16x8 v0 = *reinterpret_cast<const f16x8*>(&Vc[row * 64 + ch0]);
      f16x8 v1 = *reinterpret_cast<const f16x8*>(&Vc[row * 64 + ch1]);
      oacc[0][dt] = __builtin_amdgcn_mfma_f32_16x16x32_f16(pa[0][0], v0, oacc[0][dt], 0, 0, 0);
      oacc[0][dt] = __builtin_amdgcn_mfma_f32_16x16x32_f16(pa[0][1], v1, oacc[0][dt], 0, 0, 0);
      oacc[1][dt] = __builtin_amdgcn_mfma_f32_16x16x32_f16(pa[1][0], v0, oacc[1][dt], 0, 0, 0);
      oacc[1][dt] = __builtin_amdgcn_mfma_f32_16x16x32_f16(pa[1][1], v1, oacc[1][dt], 0, 0, 0);
    }
    __builtin_amdgcn_s_setprio(0);

    asm volatile("s_waitcnt vmcnt(0)" ::: "memory");
    __syncthreads();
  }

  // ---- epilogue: one deferred row-sum reduce, normalize, write fp16 ----
  half_t* Ob = O + ((size_t)(b * NL) + qrow0) * (NH * NHD) + (size_t)h * NHD;
#pragma unroll
  for (int rt = 0; rt < 2; ++rt)
#pragma unroll
    for (int i = 0; i < 4; ++i) {
      float l = lsum[rt][i];
#pragma unroll
      for (int off = 1; off < 16; off <<= 1)
        l += __shfl_xor(l, off);
      const float inv = 1.0f / l;
      const int rl = rt * 16 + quad * 4 + i;
#pragma unroll
      for (int dt = 0; dt < 8; ++dt)
        Ob[(size_t)rl * (NH * NHD) + dt * 16 + r16] =
            (half_t)(oacc[rt][dt][i] * inv);
    }
}

// ---------------------------------------------------------------------------
extern "C" void kernel_launch(void* const* d_in, const int* in_sizes, int n_in,
                              void* d_out, int out_size, void* d_ws, size_t ws_size,
                              hipStream_t stream) {
  const float* x  = (const float*)d_in[0];
  const float* Wq = (const float*)d_in[1];
  const float* bq = (const float*)d_in[2];
  const float* Wk = (const float*)d_in[3];
  const float* bk = (const float*)d_in[4];
  const float* Wv = (const float*)d_in[5];
  const float* bv = (const float*)d_in[6];
  const float* Wo = (const float*)d_in[7];
  float* out = (float*)d_out;

  char* ws = (char*)d_ws;
  size_t off = 0;
  auto alloc = [&](size_t bytes) {
    size_t cur = off;
    off += (bytes + 255) & ~(size_t)255;
    return cur;
  };
  const size_t M = (size_t)NB * NL;  // 4096 token rows
  // buffer plan (~186 MB):
  half_t* xb   = (half_t*)(ws + alloc(M * ND * 2));            // x fp16; reused as AttnOut
  half_t* wqkv = (half_t*)(ws + alloc((size_t)NQKV * ND * 2)); // [Wq;Wk;Wv]^T; reused for Wo^T
  half_t* rawh = (half_t*)(ws + alloc(M * NQKV * 2));          // merged QKV raw fp16
  half_t* qb   = (half_t*)(ws + alloc(M * (size_t)(NH * NHD) * 2));
  half_t* kb   = (half_t*)(ws + alloc(M * (size_t)(NKV * NHD) * 2));
  half_t* vt   = (half_t*)(ws + alloc(M * (size_t)(NKV * NHD) * 2));
  float2* tab  = (float2*)(ws + alloc((size_t)NL * 64 * 8));   // RoPE cos/sin

  // 1) x -> fp16 ; RoPE table
  {
    int n4 = (int)(M * ND / 4);
    convert_f32_f16_kernel<<<dim3((n4 + 255) / 256), dim3(256), 0, stream>>>(x, xb, n4);
  }
  ropetab_kernel<<<dim3(NL * 64 / 256), dim3(256), 0, stream>>>(tab);

  // 2) weight transposes into merged [6144][4096] fp16
  wtrans_kernel<<<dim3(ND / 32, ND / 32), dim3(32, 8), 0, stream>>>(
      Wq, wqkv, ND, ND);
  wtrans_kernel<<<dim3((NKV * NHD) / 32, ND / 32), dim3(32, 8), 0, stream>>>(
      Wk, wqkv + (size_t)ND * ND, ND, NKV * NHD);
  wtrans_kernel<<<dim3((NKV * NHD) / 32, ND / 32), dim3(32, 8), 0, stream>>>(
      Wv, wqkv + (size_t)(ND + NKV * NHD) * ND, ND, NKV * NHD);

  // 3) merged QKV GEMM -> rawh fp16 (bias fused, 3-way select)
  gemm256_kernel<half_t><<<dim3(NQKV / 256, M / 256), dim3(512), 0, stream>>>(
      xb, wqkv, bq, bk, bv, rawh, (int)M, NQKV, ND);

  // 4) RoPE+pack Q,K (table-driven); transpose V
  ropepack_kernel<<<dim3((unsigned)(M * (NH + NKV) * 64 / 256)), dim3(256), 0, stream>>>(
      rawh, tab, qb, kb);
  vtrans16_kernel<<<dim3(NL / 32, NHD / 32, NB * NKV), dim3(32, 8), 0, stream>>>(rawh, vt);

  // 5) Wo^T into wqkv (dead after step 3; stream order guarantees safety)
  wtrans_kernel<<<dim3(ND / 32, ND / 32), dim3(32, 8), 0, stream>>>(Wo, wqkv, NH * NHD, ND);

  // 6) attention -> xb (reused as AttnOut, [B*L, H*HD] fp16)
  attn_kernel<<<dim3(NB * NH * (NL / 256)), dim3(512), 0, stream>>>(qb, kb, vt, xb);

  // 7) output projection -> d_out (fp32)
  gemm256_kernel<float><<<dim3(ND / 256, M / 256), dim3(512), 0, stream>>>(
      xb, wqkv, nullptr, nullptr, nullptr, out, (int)M, ND, ND);
}

// Round 11
// 647.406 us; speedup vs baseline: 1.0930x; 1.0421x over previous
//
#include <hip/hip_runtime.h>
#include <stdint.h>
#include <stddef.h>

// ---------------------------------------------------------------------------
// Fused GQA attention block: QKV proj + half-split RoPE + flash attention +
// output proj. fp16 MFMA (16x16x32) everywhere, fp32 accumulate/softmax.
// R11: GEMM = R7 ring/swizzle/stages with phase PAIRS MERGED: 2 phases per
// K-tile, 32 MFMA per phase, ONE barrier + ONE combined vmcnt+lgkm wait per
// phase (4x less sync than R7). lgkm0 moved BEFORE the barrier so a single
// barrier provably orders reads vs the next phase's stage-writes.
// ---------------------------------------------------------------------------

typedef _Float16 half_t;
typedef __attribute__((ext_vector_type(4))) _Float16 f16x4;
typedef __attribute__((ext_vector_type(8))) _Float16 f16x8;
typedef __attribute__((ext_vector_type(4))) float f32x4;

#define NB 2
#define NL 2048
#define ND 4096
#define NH 32
#define NKV 8
#define NHD 128
#define NG 4               // H / KV
#define NQKV 6144          // H*HD + 2*KV*HD
#define QK_SCALE 0.08838834764831845f   // HD^-0.5
#define RLOG2E 1.4426950408889634f
#define M0 6.0f            // fixed softmax reference (scores ~N(0,1.64^2))
#define THR 8.0f           // defer-max threshold (fallback if mx > M0+THR)

// async global->LDS, 16B per lane. LDS dest must be wave-uniform base;
// lane i lands at base + i*16 (HW-defined linear scatter).
static __device__ __forceinline__ void gll16(const void* g, void* l) {
  __builtin_amdgcn_global_load_lds(
      (__attribute__((address_space(1))) void*)(void*)(g),
      (__attribute__((address_space(3))) void*)(l),
      16, 0, 0);
}

// ---------------------------------------------------------------------------
// elementwise fp32 -> fp16 (vectorized: float4 in, 4xfp16 out)
// ---------------------------------------------------------------------------
__global__ void convert_f32_f16_kernel(const float* __restrict__ in,
                                       half_t* __restrict__ out, int n4) {
  int i = blockIdx.x * 256 + threadIdx.x;
  if (i >= n4) return;
  const float4 v = reinterpret_cast<const float4*>(in)[i];
  f16x4 o;
  o[0] = (half_t)v.x; o[1] = (half_t)v.y; o[2] = (half_t)v.z; o[3] = (half_t)v.w;
  reinterpret_cast<f16x4*>(out)[i] = o;
}

// ---------------------------------------------------------------------------
// W [K,N] fp32 row-major  ->  Wt [N,K] fp16 row-major (LDS 32x32 tile transpose)
// ---------------------------------------------------------------------------
__global__ void wtrans_kernel(const float* __restrict__ W,
                              half_t* __restrict__ Wt, int K, int N) {
  __shared__ float tile[32][33];
  const int n0 = blockIdx.x * 32;
  const int k0 = blockIdx.y * 32;
  const int tx = threadIdx.x, ty = threadIdx.y;   // block (32,8)
#pragma unroll
  for (int r = 0; r < 32; r += 8)
    tile[ty + r][tx] = W[(size_t)(k0 + ty + r) * N + n0 + tx];
  __syncthreads();
#pragma unroll
  for (int r = 0; r < 32; r += 8)
    Wt[(size_t)(n0 + ty + r) * K + k0 + tx] = (half_t)tile[tx][ty + r];
}

// ---------------------------------------------------------------------------
// RoPE sin/cos table: tab[l*64+d] = {cos(l*invfreq(d)), sin(l*invfreq(d))}
// ---------------------------------------------------------------------------
__global__ void ropetab_kernel(float2* __restrict__ tab) {
  const int idx = blockIdx.x * 256 + threadIdx.x;   // NL*64 entries
  const int d = idx & 63;
  const int l = idx >> 6;
  const float inv_freq = exp2f(-(float)d * 0.20762050593045935f);
  const float ang = (float)l * inv_freq;
  float sn, cs;
  __sincosf(ang, &sn, &cs);
  tab[idx] = make_float2(cs, sn);
}

// ---------------------------------------------------------------------------
// GEMM: C[M,N] = A[M,K] * Bt[N,K]^T (+ 3-way bias), A/Bt fp16, C fp32/fp16.
// 256x256 tile, 8 waves (2M x 4N, each 128x64 out), BK=64 as 2 K-halves.
// LDS [2buf][2kh][256 rows][32 halfs] per array (128 KB total).
//
// R11 schedule — 2 phases per K-tile t (buf=t&1), 32 MFMA each:
//  PA: ds_read af,bf,ah (kc0, 12 reads); stage A,B(t+1)kc1 (4 loads);
//      s_waitcnt vmcnt(8) lgkmcnt(0); BARRIER; 32 MFMA (kc0).
//  PB: ds_read af,bf,ah (kc1, 12 reads); stage A,B(t+2)kc0 (4 loads);
//      s_waitcnt vmcnt(8) lgkmcnt(0); BARRIER; 32 MFMA (kc1).
//
// RAW (residency before reads): (t)k0 retired by PB(t-1)'s vmcnt(8)
//   [outstanding there = (t)k0,(t)k1,(t+1)k0 = 12 -> retires oldest 4] +
//   barrier; (t)k1 retired by PA(t)'s vmcnt(8) [(t)k1,(t+1)k0,(t+1)k1=12]
//   + barrier. Prologue vm8+barrier covers (0)k0.
// WAR (stage vs readers): lgkm0 is BEFORE each barrier, so every wave's
//   ds_reads of phase P are complete when it reaches P's barrier; the slot
//   staged in the NEXT phase (issued after that barrier) cannot race them.
//   PA(t) stages slot[(t+1)&1][1] (occupant (t-1)k1, read PB(t-1));
//   PB(t) stages slot[t&1][0] (occupant (t)k0, read PA(t)).
// Tail: PA(NT-1): vm4 (retire (NT-1)k0); PB(NT-2): vm8 no-op; PB(NT-1): vm0.
// Swizzle: global chunk cg at LDS chunk cg^((row>>1)&3); reads use
// csw = (quad ^ ((r16>>1)&3)) -> measured 0 bank conflicts.
// ---------------------------------------------------------------------------
template <typename OutT>
__global__ __launch_bounds__(512, 2) void gemm256_kernel(
    const half_t* __restrict__ A, const half_t* __restrict__ Bt,
    const float* __restrict__ B0, const float* __restrict__ B1,
    const float* __restrict__ B2, OutT* __restrict__ C,
    int M, int N, int K) {
  __shared__ __align__(16) half_t As[2][2][256 * 32];   // [buf][kh] 16KB each
  __shared__ __align__(16) half_t Bs[2][2][256 * 32];

  const int tid = threadIdx.x;
  const int wave = tid >> 6, lane = tid & 63;
  const int r16 = lane & 15, quad = lane >> 4;
  const int wm = wave >> 2, wn = wave & 3;   // 2M x 4N wave grid

  // T1: XCD-chunked swizzle of linear block id (nwg % 8 == 0 for our grids)
  const int nbx = N >> 8;
  const int lid = (int)(blockIdx.y * gridDim.x + blockIdx.x);
  const int nwg = (int)(gridDim.x * gridDim.y);
  const int cpx = nwg >> 3;
  const int swz = (lid & 7) * cpx + (lid >> 3);
  const int brow = (swz / nbx) * 256;
  const int bcol = (swz % nbx) * 256;

  const int NT = K >> 6;   // K/64 tiles

  // half-tile stage: 256 rows x 32 halfs (64B/row), 1024 slots, 2/thread.
  // slot s: row=s>>2, LDS chunk s&3 holds global chunk (s&3)^((row>>1)&3).
  auto stA = [&](int t, int kh) {
    const int buf = t & 1;
    const int k0 = (t << 6) + (kh << 5);
#pragma unroll
    for (int j = 0; j < 2; ++j) {
      const int s = j * 512 + wave * 64 + lane;
      const int row = s >> 2;
      const int cg = (s & 3) ^ ((row >> 1) & 3);
      gll16(A + (size_t)(brow + row) * K + k0 + cg * 8,
            &As[buf][kh][(j * 512 + wave * 64) * 8]);
    }
  };
  auto stB = [&](int t, int kh) {
    const int buf = t & 1;
    const int k0 = (t << 6) + (kh << 5);
#pragma unroll
    for (int j = 0; j < 2; ++j) {
      const int s = j * 512 + wave * 64 + lane;
      const int row = s >> 2;
      const int cg = (s & 3) ^ ((row >> 1) & 3);
      gll16(Bt + (size_t)(bcol + row) * K + k0 + cg * 8,
            &Bs[buf][kh][(j * 512 + wave * 64) * 8]);
    }
  };

  f32x4 acc[8][4] = {};
  const int csw = (quad ^ ((r16 >> 1) & 3)) << 3;   // swizzled chunk (halfs)

  // prologue: (0)k0,(0)k1,(1)k0 = 12 loads; retire tile0 kc0 (vmcnt(8))
  stA(0, 0); stB(0, 0); stA(0, 1); stB(0, 1); stA(1, 0); stB(1, 0);
  asm volatile("s_waitcnt vmcnt(8)" ::: "memory");
  __builtin_amdgcn_s_barrier();

  for (int t = 0; t < NT; ++t) {
    const int buf = t & 1;
    const half_t* Ak0 = &As[buf][0][0];
    const half_t* Ak1 = &As[buf][1][0];
    const half_t* Bk0 = &Bs[buf][0][0];
    const half_t* Bk1 = &Bs[buf][1][0];
    f16x8 af[4], bf[4], ah[4];

    // ============ PA: kc0, 32 MFMA ============
#pragma unroll
    for (int mi = 0; mi < 4; ++mi)
      af[mi] = *reinterpret_cast<const f16x8*>(
          &Ak0[(wm * 128 + mi * 16 + r16) * 32 + csw]);
#pragma unroll
    for (int ni = 0; ni < 4; ++ni)
      bf[ni] = *reinterpret_cast<const f16x8*>(
          &Bk0[(wn * 64 + ni * 16 + r16) * 32 + csw]);
#pragma unroll
    for (int mi = 0; mi < 4; ++mi)
      ah[mi] = *reinterpret_cast<const f16x8*>(
          &Ak0[(wm * 128 + 64 + mi * 16 + r16) * 32 + csw]);
    if (t + 1 < NT) {
      stA(t + 1, 1); stB(t + 1, 1);
      asm volatile("s_waitcnt vmcnt(8) lgkmcnt(0)" ::: "memory");
    } else {
      asm volatile("s_waitcnt vmcnt(4) lgkmcnt(0)" ::: "memory");
    }
    __builtin_amdgcn_sched_barrier(0);
    __builtin_amdgcn_s_barrier();
    __builtin_amdgcn_sched_barrier(0);
    __builtin_amdgcn_s_setprio(1);
#pragma unroll
    for (int mi = 0; mi < 4; ++mi)
#pragma unroll
      for (int ni = 0; ni < 4; ++ni)
        acc[mi][ni] = __builtin_amdgcn_mfma_f32_16x16x32_f16(
            af[mi], bf[ni], acc[mi][ni], 0, 0, 0);
#pragma unroll
    for (int mi = 0; mi < 4; ++mi)
#pragma unroll
      for (int ni = 0; ni < 4; ++ni)
        acc[mi + 4][ni] = __builtin_amdgcn_mfma_f32_16x16x32_f16(
            ah[mi], bf[ni], acc[mi + 4][ni], 0, 0, 0);
    __builtin_amdgcn_s_setprio(0);

    // ============ PB: kc1, 32 MFMA ============
#pragma unroll
    for (int mi = 0; mi < 4; ++mi)
      af[mi] = *reinterpret_cast<const f16x8*>(
          &Ak1[(wm * 128 + mi * 16 + r16) * 32 + csw]);
#pragma unroll
    for (int ni = 0; ni < 4; ++ni)
      bf[ni] = *reinterpret_cast<const f16x8*>(
          &Bk1[(wn * 64 + ni * 16 + r16) * 32 + csw]);
#pragma unroll
    for (int mi = 0; mi < 4; ++mi)
      ah[mi] = *reinterpret_cast<const f16x8*>(
          &Ak1[(wm * 128 + 64 + mi * 16 + r16) * 32 + csw]);
    if (t + 2 < NT) {
      stA(t + 2, 0); stB(t + 2, 0);
      asm volatile("s_waitcnt vmcnt(8) lgkmcnt(0)" ::: "memory");
    } else if (t + 1 < NT) {
      asm volatile("s_waitcnt vmcnt(8) lgkmcnt(0)" ::: "memory");
    } else {
      asm volatile("s_waitcnt vmcnt(0) lgkmcnt(0)" ::: "memory");
    }
    __builtin_amdgcn_sched_barrier(0);
    __builtin_amdgcn_s_barrier();
    __builtin_amdgcn_sched_barrier(0);
    __builtin_amdgcn_s_setprio(1);
#pragma unroll
    for (int mi = 0; mi < 4; ++mi)
#pragma unroll
      for (int ni = 0; ni < 4; ++ni)
        acc[mi][ni] = __builtin_amdgcn_mfma_f32_16x16x32_f16(
            af[mi], bf[ni], acc[mi][ni], 0, 0, 0);
#pragma unroll
    for (int mi = 0; mi < 4; ++mi)
#pragma unroll
      for (int ni = 0; ni < 4; ++ni)
        acc[mi + 4][ni] = __builtin_amdgcn_mfma_f32_16x16x32_f16(
            ah[mi], bf[ni], acc[mi + 4][ni], 0, 0, 0);
    __builtin_amdgcn_s_setprio(0);
  }

  // epilogue: D row = (lane>>4)*4 + reg, col = lane&15 (verified C/D layout)
#pragma unroll
  for (int ni = 0; ni < 4; ++ni) {
    const int col = bcol + wn * 64 + ni * 16 + r16;
    float bv = 0.0f;
    if (B0) bv = (col < ND) ? B0[col]
                            : (col < ND + NKV * NHD ? B1[col - ND]
                                                    : B2[col - ND - NKV * NHD]);
#pragma unroll
    for (int mi = 0; mi < 8; ++mi) {
      const int row0 = brow + wm * 128 + mi * 16 + quad * 4;
#pragma unroll
      for (int i = 0; i < 4; ++i)
        C[(size_t)(row0 + i) * N + col] = (OutT)(acc[mi][ni][i] + bv);
    }
  }
}

// ---------------------------------------------------------------------------
// RoPE (half-split, table-driven) + reshape for Q and K from merged raw fp16.
// hp<32: Q head hp (QK_SCALE folded); else K head hp-32.
// ---------------------------------------------------------------------------
__global__ void ropepack_kernel(const half_t* __restrict__ rawh,
                                const float2* __restrict__ tab,
                                half_t* __restrict__ qb,
                                half_t* __restrict__ kb) {
  const size_t idx = (size_t)blockIdx.x * 256 + threadIdx.x;
  const int d = (int)(idx & 63);
  size_t t = idx >> 6;
  const int hp = (int)(t % (NH + NKV)); t /= (NH + NKV);
  const int l = (int)(t % NL);
  const int b = (int)(t / NL);
  const bool isQ = hp < NH;
  const int col0 = isQ ? hp * NHD : ND + (hp - NH) * NHD;
  const half_t* src = rawh + ((size_t)b * NL + l) * NQKV + col0;
  const float x1 = (float)src[d];
  const float x2 = (float)src[d + 64];
  const float2 cssn = tab[(size_t)l * 64 + d];
  const float scale = isQ ? QK_SCALE : 1.0f;
  half_t* dst = isQ ? qb + ((size_t)(b * NH + hp) * NL + l) * NHD
                    : kb + ((size_t)(b * NKV + (hp - NH)) * NL + l) * NHD;
  dst[d]      = (half_t)((x1 * cssn.x - x2 * cssn.y) * scale);
  dst[d + 64] = (half_t)((x2 * cssn.x + x1 * cssn.y) * scale);
}

// ---------------------------------------------------------------------------
// V: merged raw fp16 cols [5120,6144) -> Vt [B, KV, HD, L] fp16 (transpose)
// ---------------------------------------------------------------------------
__global__ void vtrans16_kernel(const half_t* __restrict__ rawh,
                                half_t* __restrict__ Vt) {
  __shared__ half_t tile[32][34];
  const int bkv = blockIdx.z;
  const int l0 = blockIdx.x * 32;
  const int d0 = blockIdx.y * 32;
  const int b = bkv / NKV, kvh = bkv % NKV;
  const int tx = threadIdx.x, ty = threadIdx.y;   // block (32,8)
#pragma unroll
  for (int r = 0; r < 32; r += 8)
    tile[ty + r][tx] = rawh[(size_t)(b * NL + l0 + ty + r) * NQKV
                            + ND + NKV * NHD + kvh * NHD + d0 + tx];
  __syncthreads();
  half_t* dst = Vt + (size_t)bkv * NHD * NL;
#pragma unroll
  for (int r = 0; r < 32; r += 8)
    dst[(size_t)(d0 + ty + r) * NL + l0 + tx] = tile[tx][ty + r];
}

// ---------------------------------------------------------------------------
// Flash attention (non-causal, GQA). 8 waves x 32 Q-rows = 256 rows/block.
// K/V tiles (64 keys) LDS-staged via global_load_lds, double-buffered,
// XOR chunk-swizzled. Softmax: fixed reference M0 (no per-tile max reduce),
// per-lane deferred row-sum (one reduce in epilogue), rare wave-uniform
// fallback rescale keeps arbitrary-data correctness. T5 setprio on MFMA.
// ---------------------------------------------------------------------------
#define KVB 64

__global__ __launch_bounds__(512, 2) void attn_kernel(
    const half_t* __restrict__ Q,   // [B,H,L,HD] scaled
    const half_t* __restrict__ Kh,  // [B,KV,L,HD]
    const half_t* __restrict__ Vt,  // [B,KV,HD,L]
    half_t* __restrict__ O) {
  __shared__ half_t Ks[2][KVB * NHD];   // 2 x 16KB
  __shared__ half_t Vs[2][NHD * KVB];   // 2 x 16KB
  __shared__ half_t Ps[8][16 * 64];     // 16KB, per-wave P tile

  const int tid = threadIdx.x;
  const int wave = tid >> 6, lane = tid & 63;
  const int r16 = lane & 15, quad = lane >> 4;
  const int r7 = r16 & 7;

  // XCD-chunked swizzle: 64 consecutive work-items per XCD (512 = 8*64)
  const int bid = (int)blockIdx.x;
  const int swz = (bid & 7) * 64 + (bid >> 3);
  const int nqt = NL / 256;                    // 8
  const int bh = swz / nqt, qt = swz % nqt;
  const int b = bh / NH, h = bh % NH;
  const int kvh = h / NG;

  const int qrow0 = qt * 256 + wave * 32;
  const half_t* Qb = Q  + ((size_t)(b * NH + h) * NL + qrow0) * NHD;
  const half_t* Kb = Kh + ((size_t)(b * NKV + kvh) * NL) * NHD;
  const half_t* Vb = Vt + ((size_t)(b * NKV + kvh) * NHD) * NL;
  half_t* Pw = &Ps[wave][0];

  // ---- stage(buf, n0): K tile 1024 slots, V tile 1024 slots (16B each) ----
  auto stage = [&](int buf, int n0) {
#pragma unroll
    for (int j = 0; j < 2; ++j) {
      const int slot = j * 512 + wave * 64 + lane;
      {
        const int row = slot >> 4;                    // key row 0..63
        const int c = (slot & 15) ^ (row & 7);        // global chunk
        gll16(Kb + (size_t)(n0 + row) * NHD + c * 8,
              &Ks[buf][(j * 512 + wave * 64) * 8]);
      }
      {
        const int row = slot >> 3;                    // d row 0..127
        const int c = (slot & 7) ^ (row & 7);
        gll16(Vb + (size_t)row * NL + n0 + c * 8,
              &Vs[buf][(j * 512 + wave * 64) * 8]);
      }
    }
  };

  stage(0, 0);

  // Q fragments: 2 row-tiles x 4 k-chunks
  f16x8 qf[2][4];
#pragma unroll
  for (int rt = 0; rt < 2; ++rt)
#pragma unroll
    for (int c = 0; c < 4; ++c)
      qf[rt][c] = *reinterpret_cast<const f16x8*>(
          &Qb[(size_t)(rt * 16 + r16) * NHD + c * 32 + quad * 8]);

  f32x4 oacc[2][8];
  float m_run[2][4], lsum[2][4];
#pragma unroll
  for (int rt = 0; rt < 2; ++rt) {
#pragma unroll
    for (int i = 0; i < 4; ++i) { m_run[rt][i] = M0; lsum[rt][i] = 0.0f; }
#pragma unroll
    for (int dt = 0; dt < 8; ++dt) oacc[rt][dt] = (f32x4){0.f, 0.f, 0.f, 0.f};
  }

  // P read swizzle (row = r16): mask = (r16&7) ^ ((r16>>3)*5)
  const int swzread = r7 ^ ((r16 >> 3) * 5);

  asm volatile("s_waitcnt vmcnt(0)" ::: "memory");
  __syncthreads();

  int cur = 0;
  for (int t = 0; t < NL / KVB; ++t, cur ^= 1) {
    if (t + 1 < NL / KVB) stage(cur ^ 1, (t + 1) * KVB);

    const half_t* Kc = &Ks[cur][0];
    const half_t* Vc = &Vs[cur][0];

    // ---- S = Q K^T (swizzled K reads) ----
    f32x4 s[2][4] = {};
    __builtin_amdgcn_s_setprio(1);
#pragma unroll
    for (int c = 0; c < 4; ++c) {
      const int ch = ((c * 4 + quad) ^ r7) * 8;
#pragma unroll
      for (int nt = 0; nt < 4; ++nt) {
        f16x8 kf = *reinterpret_cast<const f16x8*>(&Kc[(nt * 16 + r16) * NHD + ch]);
        s[0][nt] = __builtin_amdgcn_mfma_f32_16x16x32_f16(qf[0][c], kf, s[0][nt], 0, 0, 0);
        s[1][nt] = __builtin_amdgcn_mfma_f32_16x16x32_f16(qf[1][c], kf, s[1][nt], 0, 0, 0);
      }
    }
    __builtin_amdgcn_s_setprio(0);

    // ---- fallback check: any lane-local score above M0+THR? (no reduce) ----
    float mx[2][4];
    bool need = false;
#pragma unroll
    for (int rt = 0; rt < 2; ++rt)
#pragma unroll
      for (int i = 0; i < 4; ++i) {
        mx[rt][i] = fmaxf(fmaxf(s[rt][0][i], s[rt][1][i]),
                          fmaxf(s[rt][2][i], s[rt][3][i]));
        need = need || (mx[rt][i] > m_run[rt][i] + THR);
      }
    if (__any(need ? 1 : 0)) {   // rare: full reduce + rescale (correctness)
#pragma unroll
      for (int rt = 0; rt < 2; ++rt)
#pragma unroll
        for (int i = 0; i < 4; ++i) {
          float m = mx[rt][i];
#pragma unroll
          for (int off = 1; off < 16; off <<= 1)
            m = fmaxf(m, __shfl_xor(m, off));
          const float mn = fmaxf(m_run[rt][i], m);
          const float corr = exp2f((m_run[rt][i] - mn) * RLOG2E);
          m_run[rt][i] = mn;
          lsum[rt][i] *= corr;
#pragma unroll
          for (int dt = 0; dt < 8; ++dt) oacc[rt][dt][i] *= corr;
        }
    }

    // ---- P = exp(S - m), per-lane partial sums, swizzled LDS writes ----
    f16x8 pa[2][2];
#pragma unroll
    for (int rt = 0; rt < 2; ++rt) {
#pragma unroll
      for (int i = 0; i < 4; ++i) {
        const float mrl = m_run[rt][i] * RLOG2E;
        float p[4];
#pragma unroll
        for (int nt = 0; nt < 4; ++nt)
          p[nt] = exp2f(s[rt][nt][i] * RLOG2E - mrl);
        lsum[rt][i] += (p[0] + p[1]) + (p[2] + p[3]);
        const int row = quad * 4 + i;
        const int swzr = (row & 7) ^ ((row >> 3) * 5);
#pragma unroll
        for (int nt = 0; nt < 4; ++nt)
          Pw[row * 64 + (((nt * 2 + (r16 >> 3)) ^ swzr) * 8) + r7] = (half_t)p[nt];
      }
      // A-fragments (wave-private LDS; in-order DS pipe, no barrier)
      pa[rt][0] = *reinterpret_cast<const f16x8*>(&Pw[r16 * 64 + ((quad ^ swzread) * 8)]);
      pa[rt][1] = *reinterpret_cast<const f16x8*>(&Pw[r16 * 64 + (((4 + quad) ^ swzread) * 8)]);
    }

    // ---- O += P V (swizzled V reads, shared across both row-tiles) ----
    const int ch0 = (quad ^ r7) * 8;
    const int ch1 = ((4 + quad) ^ r7) * 8;
    __builtin_amdgcn_s_setprio(1);
#pragma unroll
    for (int dt = 0; dt < 8; ++dt) {
      const int row = dt * 16 + r16;
      f16x8 v0 = *reinterpret_cast<const f16x8*>(&Vc[row * 64 + ch0]);
      f16x8 v1 = *reinterpret_cast<const f16x8*>(&Vc[row * 64 + ch1]);
      oacc[0][dt] = __builtin_amdgcn_mfma_f32_16x16x32_f16(pa[0][0], v0, oacc[0][dt], 0, 0, 0);
      oacc[0][dt] = __builtin_amdgcn_mfma_f32_16x16x32_f16(pa[0][1], v1, oacc[0][dt], 0, 0, 0);
      oacc[1][dt] = __builtin_amdgcn_mfma_f32_16x16x32_f16(pa[1][0], v0, oacc[1][dt], 0, 0, 0);
      oacc[1][dt] = __builtin_amdgcn_mfma_f32_16x16x32_f16(pa[1][1], v1, oacc[1][dt], 0, 0, 0);
    }
    __builtin_amdgcn_s_setprio(0);

    asm volatile("s_waitcnt vmcnt(0)" ::: "memory");
    __syncthreads();
  }

  // ---- epilogue: one deferred row-sum reduce, normalize, write fp16 ----
  half_t* Ob = O + ((size_t)(b * NL) + qrow0) * (NH * NHD) + (size_t)h * NHD;
#pragma unroll
  for (int rt = 0; rt < 2; ++rt)
#pragma unroll
    for (int i = 0; i < 4; ++i) {
      float l = lsum[rt][i];
#pragma unroll
      for (int off = 1; off < 16; off <<= 1)
        l += __shfl_xor(l, off);
      const float inv = 1.0f / l;
      const int rl = rt * 16 + quad * 4 + i;
#pragma unroll
      for (int dt = 0; dt < 8; ++dt)
        Ob[(size_t)rl * (NH * NHD) + dt * 16 + r16] =
            (half_t)(oacc[rt][dt][i] * inv);
    }
}

// ---------------------------------------------------------------------------
extern "C" void kernel_launch(void* const* d_in, const int* in_sizes, int n_in,
                              void* d_out, int out_size, void* d_ws, size_t ws_size,
                              hipStream_t stream) {
  const float* x  = (const float*)d_in[0];
  const float* Wq = (const float*)d_in[1];
  const float* bq = (const float*)d_in[2];
  const float* Wk = (const float*)d_in[3];
  const float* bk = (const float*)d_in[4];
  const float* Wv = (const float*)d_in[5];
  const float* bv = (const float*)d_in[6];
  const float* Wo = (const float*)d_in[7];
  float* out = (float*)d_out;

  char* ws = (char*)d_ws;
  size_t off = 0;
  auto alloc = [&](size_t bytes) {
    size_t cur = off;
    off += (bytes + 255) & ~(size_t)255;
    return cur;
  };
  const size_t M = (size_t)NB * NL;  // 4096 token rows
  // buffer plan (~186 MB):
  half_t* xb   = (half_t*)(ws + alloc(M * ND * 2));            // x fp16; reused as AttnOut
  half_t* wqkv = (half_t*)(ws + alloc((size_t)NQKV * ND * 2)); // [Wq;Wk;Wv]^T; reused for Wo^T
  half_t* rawh = (half_t*)(ws + alloc(M * NQKV * 2));          // merged QKV raw fp16
  half_t* qb   = (half_t*)(ws + alloc(M * (size_t)(NH * NHD) * 2));
  half_t* kb   = (half_t*)(ws + alloc(M * (size_t)(NKV * NHD) * 2));
  half_t* vt   = (half_t*)(ws + alloc(M * (size_t)(NKV * NHD) * 2));
  float2* tab  = (float2*)(ws + alloc((size_t)NL * 64 * 8));   // RoPE cos/sin

  // 1) x -> fp16 ; RoPE table
  {
    int n4 = (int)(M * ND / 4);
    convert_f32_f16_kernel<<<dim3((n4 + 255) / 256), dim3(256), 0, stream>>>(x, xb, n4);
  }
  ropetab_kernel<<<dim3(NL * 64 / 256), dim3(256), 0, stream>>>(tab);

  // 2) weight transposes into merged [6144][4096] fp16
  wtrans_kernel<<<dim3(ND / 32, ND / 32), dim3(32, 8), 0, stream>>>(
      Wq, wqkv, ND, ND);
  wtrans_kernel<<<dim3((NKV * NHD) / 32, ND / 32), dim3(32, 8), 0, stream>>>(
      Wk, wqkv + (size_t)ND * ND, ND, NKV * NHD);
  wtrans_kernel<<<dim3((NKV * NHD) / 32, ND / 32), dim3(32, 8), 0, stream>>>(
      Wv, wqkv + (size_t)(ND + NKV * NHD) * ND, ND, NKV * NHD);

  // 3) merged QKV GEMM -> rawh fp16 (bias fused, 3-way select)
  gemm256_kernel<half_t><<<dim3(NQKV / 256, M / 256), dim3(512), 0, stream>>>(
      xb, wqkv, bq, bk, bv, rawh, (int)M, NQKV, ND);

  // 4) RoPE+pack Q,K (table-driven); transpose V
  ropepack_kernel<<<dim3((unsigned)(M * (NH + NKV) * 64 / 256)), dim3(256), 0, stream>>>(
      rawh, tab, qb, kb);
  vtrans16_kernel<<<dim3(NL / 32, NHD / 32, NB * NKV), dim3(32, 8), 0, stream>>>(rawh, vt);

  // 5) Wo^T into wqkv (dead after step 3; stream order guarantees safety)
  wtrans_kernel<<<dim3(ND / 32, ND / 32), dim3(32, 8), 0, stream>>>(Wo, wqkv, NH * NHD, ND);

  // 6) attention -> xb (reused as AttnOut, [B*L, H*HD] fp16)
  attn_kernel<<<dim3(NB * NH * (NL / 256)), dim3(512), 0, stream>>>(qb, kb, vt, xb);

  // 7) output projection -> d_out (fp32)
  gemm256_kernel<float><<<dim3(ND / 256, M / 256), dim3(512), 0, stream>>>(
      xb, wqkv, nullptr, nullptr, nullptr, out, (int)M, ND, ND);
}